// Round 2
// baseline (3620.710 us; speedup 1.0000x reference)
//
#include <hip/hip_runtime.h>
#include <cmath>

// DHGLayer on MI355X. N=10000, D=128. Pipeline:
//  knorm (f32 xn + f64 norms) -> ksimtopk (fp32 GEMM + per-chunk top-16) ->
//  kmerge (global top-32 candidates by fp32 key) -> krerank (f64 exact top-16)
//  -> per branch: kmult (mult GEMM) + kvconv2 (softmax/coef/gather) -> kfinal.
// Vertex conv collapsed: out = sum_j coef[j]*x[j,:] with
// coef[j] = sum_i wK1[i]*softmax_row_i(mult)[j]  (halves the FLOPs).
// f64 re-rank kills top-k flips vs the f64 numpy reference (rank-16 gap
// ~1.7e-3 vs fp32 GEMM noise ~1e-6 caused ~8 flipped rows -> 5.7e-3 absmax).

#define N_NODES 10000
#define D 128
#define DQ 32          // float4s per feature row
#define NCB 3          // n_center
#define T_HE 5         // hyperedge count
#define HID_SZ 32
#define NCH 16         // top-k column chunks
#define CHUNK 640      // 5 tiles of 128 cols
#define TOPK 16
#define TOPM 32        // f64 re-rank candidate count

// ---------------- normalize + f64 norm ----------------
__global__ __launch_bounds__(64) void knorm(const float* __restrict__ feats,
                                            float* __restrict__ xn,
                                            double* __restrict__ normD) {
  int n = blockIdx.x;
  int lane = threadIdx.x;
  const float2* f2 = (const float2*)(feats + (size_t)n * D);
  float2 v = f2[lane];
  double ss = (double)v.x * (double)v.x + (double)v.y * (double)v.y;
#pragma unroll
  for (int o = 32; o > 0; o >>= 1) ss += __shfl_xor(ss, o);
  double nd = fmax(sqrt(ss), 1e-12);
  if (lane == 0) normD[n] = nd;
  float inv = (float)(1.0 / nd);
  float2 r; r.x = v.x * inv; r.y = v.y * inv;
  ((float2*)(xn + (size_t)n * D))[lane] = r;
}

// monotonic fp32 key + inverted index for jax top_k tie-break (lower idx first)
__device__ __forceinline__ unsigned long long simkey(float v, int col) {
  unsigned int b = __float_as_uint(v);
  unsigned int mu = (b & 0x80000000u) ? ~b : (b | 0x80000000u);
  return ((unsigned long long)mu << 32) | (unsigned long long)(~(unsigned int)col);
}

template <int S>
__device__ __forceinline__ void topk_insert(unsigned long long (&keys)[S],
                                            unsigned long long& thresh,
                                            unsigned long long key) {
  int mslot = 0;
  unsigned long long mk = keys[0];
#pragma unroll
  for (int s = 1; s < S; s++) { if (keys[s] < mk) { mk = keys[s]; mslot = s; } }
#pragma unroll
  for (int s = 0; s < S; s++) { if (s == mslot) keys[s] = key; }  // keeps array in VGPRs
  unsigned long long t2 = keys[0];
#pragma unroll
  for (int s = 1; s < S; s++) t2 = (keys[s] < t2) ? keys[s] : t2;
  thresh = t2;
}

// ---------------- fused sim GEMM + chunked top-16 ----------------
// grid (79 row-blocks of 128, NCH chunks). 128x128 col tiles, k-chunk 16,
// transposed LDS staging, 8x8 per-thread register tile (1 LDS byte / MAC).
__global__ __launch_bounds__(256) void ksimtopk(const float* __restrict__ xn,
                                                unsigned long long* __restrict__ cand) {
  __shared__ float AT[16][132];     // [k][row]
  __shared__ float BT[16][132];     // [k][col]
  __shared__ float simT[128][65];   // one 128x64 half at a time
  int tid = threadIdx.x;
  int row0 = blockIdx.x * 128;
  int chunk = blockIdx.y;
  int cbase = chunk * CHUNK;
  int cend = min(cbase + CHUNK, N_NODES);
  int u = tid & 15;    // row quads: 4u and 64+4u
  int vq = tid >> 4;   // col quads: 4vq and 64+4vq
  unsigned long long keys[TOPK];
#pragma unroll
  for (int s = 0; s < TOPK; s++) keys[s] = 0ull;
  unsigned long long thresh = 0ull;
  const float4* xn4 = (const float4*)xn;

  for (int tb = cbase; tb < cend; tb += 128) {
    float acc[2][2][4][4];
#pragma unroll
    for (int ra = 0; ra < 2; ra++)
#pragma unroll
      for (int ca = 0; ca < 2; ca++)
#pragma unroll
        for (int m = 0; m < 4; m++)
#pragma unroll
          for (int j = 0; j < 4; j++) acc[ra][ca][m][j] = 0.f;

    for (int kc = 0; kc < D; kc += 16) {
      __syncthreads();  // prev compute / prev scan done
      for (int q = tid; q < 512; q += 256) {     // stage A transposed
        int r = q & 127, kg = q >> 7;
        int row = row0 + r;
        float4 val = make_float4(0.f, 0.f, 0.f, 0.f);
        if (row < N_NODES) val = xn4[(size_t)row * DQ + (kc >> 2) + kg];
        int kl = kg << 2;
        AT[kl + 0][r] = val.x; AT[kl + 1][r] = val.y;
        AT[kl + 2][r] = val.z; AT[kl + 3][r] = val.w;
      }
      for (int q = tid; q < 512; q += 256) {     // stage B transposed
        int c = q & 127, kg = q >> 7;
        int col = tb + c;
        float4 val = make_float4(0.f, 0.f, 0.f, 0.f);
        if (col < N_NODES) val = xn4[(size_t)col * DQ + (kc >> 2) + kg];
        int kl = kg << 2;
        BT[kl + 0][c] = val.x; BT[kl + 1][c] = val.y;
        BT[kl + 2][c] = val.z; BT[kl + 3][c] = val.w;
      }
      __syncthreads();
#pragma unroll
      for (int k = 0; k < 16; k++) {
        float4 a0 = *(const float4*)&AT[k][u << 2];
        float4 a1 = *(const float4*)&AT[k][64 + (u << 2)];
        float4 b0 = *(const float4*)&BT[k][vq << 2];
        float4 b1 = *(const float4*)&BT[k][64 + (vq << 2)];
        float am[2][4] = {{a0.x, a0.y, a0.z, a0.w}, {a1.x, a1.y, a1.z, a1.w}};
        float bm[2][4] = {{b0.x, b0.y, b0.z, b0.w}, {b1.x, b1.y, b1.z, b1.w}};
#pragma unroll
        for (int ra = 0; ra < 2; ra++)
#pragma unroll
          for (int ca = 0; ca < 2; ca++)
#pragma unroll
            for (int m = 0; m < 4; m++)
#pragma unroll
              for (int j = 0; j < 4; j++)
                acc[ra][ca][m][j] = fmaf(am[ra][m], bm[ca][j], acc[ra][ca][m][j]);
      }
    }
    // two 64-col halves: write -> scan
#pragma unroll
    for (int h = 0; h < 2; h++) {
      if (h == 1) __syncthreads();   // scan of half 0 done
#pragma unroll
      for (int ra = 0; ra < 2; ra++)
#pragma unroll
        for (int m = 0; m < 4; m++)
#pragma unroll
          for (int j = 0; j < 4; j++)
            simT[ra * 64 + (u << 2) + m][(vq << 2) + j] = acc[ra][h][m][j];
      __syncthreads();
      if (tid < 128) {
        int row = row0 + tid;
        if (row < N_NODES) {
          int base = tb + h * 64;
          int lim = min(64, cend - base);
          for (int c = 0; c < lim; c++) {
            unsigned long long key = simkey(simT[tid][c], base + c);
            if (key > thresh) topk_insert<TOPK>(keys, thresh, key);
          }
        }
      }
    }
  }
  if (tid < 128) {
    int row = row0 + tid;
    if (row < N_NODES) {
      unsigned long long* o = cand + ((size_t)row * NCH + chunk) * TOPK;
#pragma unroll
      for (int s = 0; s < TOPK; s++) o[s] = keys[s];
    }
  }
}

// ---------------- merge chunk candidates -> top-32 candidate indices ----------------
__global__ __launch_bounds__(256) void kmerge(const unsigned long long* __restrict__ cand,
                                              int* __restrict__ candIdx) {
  int row = blockIdx.x * 256 + threadIdx.x;
  if (row >= N_NODES) return;
  unsigned long long keys[TOPM];
#pragma unroll
  for (int s = 0; s < TOPM; s++) keys[s] = 0ull;
  unsigned long long thresh = 0ull;
  const unsigned long long* c = cand + (size_t)row * (NCH * TOPK);
  for (int s = 0; s < NCH * TOPK; s++) {
    unsigned long long k = c[s];
    if (k > thresh) topk_insert<TOPM>(keys, thresh, k);
  }
#pragma unroll
  for (int s = 0; s < TOPM; s++)
    candIdx[(size_t)row * TOPM + s] = (int)(~(unsigned int)(keys[s] & 0xFFFFFFFFull));
}

// ---------------- f64 exact re-rank of 32 candidates -> knn top-16 ----------------
// one block per row; 8 threads per candidate.
__global__ __launch_bounds__(256) void krerank(const float* __restrict__ feats,
                                               const double* __restrict__ normD,
                                               const int* __restrict__ candIdx,
                                               int* __restrict__ knn) {
  __shared__ float rowF[D];
  __shared__ double simL[TOPM];
  __shared__ int idxL[TOPM];
  int row = blockIdx.x;
  int tid = threadIdx.x;
  if (tid < DQ)
    ((float4*)rowF)[tid] = ((const float4*)(feats + (size_t)row * D))[tid];
  int c = tid >> 3, part = tid & 7;
  int cnd = candIdx[(size_t)row * TOPM + c];
  __syncthreads();
  const float4* f4 = (const float4*)(feats + (size_t)cnd * D);
  double acc = 0.0;
#pragma unroll
  for (int g = 0; g < 4; g++) {
    float4 v = f4[part * 4 + g];
    const float* rf = &rowF[(part * 4 + g) * 4];
    acc = fma((double)v.x, (double)rf[0], acc);
    acc = fma((double)v.y, (double)rf[1], acc);
    acc = fma((double)v.z, (double)rf[2], acc);
    acc = fma((double)v.w, (double)rf[3], acc);
  }
  acc += __shfl_down(acc, 4);
  acc += __shfl_down(acc, 2);
  acc += __shfl_down(acc, 1);
  if (part == 0) {
    simL[c] = acc / (normD[row] * normD[cnd]);
    idxL[c] = cnd;
  }
  __syncthreads();
  if (tid < TOPM) {
    double s = simL[tid];
    int idx = idxL[tid];
    int rank = 0;
#pragma unroll
    for (int o = 0; o < TOPM; o++) {
      double so = simL[o];
      int io = idxL[o];
      rank += (so > s || (so == s && io < idx)) ? 1 : 0;
    }
    if (rank < TOPK) knn[(size_t)row * TOPK + rank] = idx;
  }
}

// ---------------- mult GEMM: mult[n,i,j] = <x[n,idx_i], wKK[i,j,:]> + bKK ----------------
// grid (79 node-blocks of 128, K). Threads = 8*K (128 or 256). 4x4 per-thread tile.
template <int K>
__global__ __launch_bounds__(256) void kmult(const float* __restrict__ feats,
    const int* __restrict__ idxTab, int idxStride, int idxOff,
    const float* __restrict__ wKK, const float* __restrict__ bKK,
    float* __restrict__ multBuf) {
  constexpr int NT = 8 * K;
  constexpr int JG = K / 4;
  __shared__ float ATl[32][132];      // [k][node]
  __shared__ float WTl[32][K + 4];    // [k][j]
  __shared__ int idxL[128];
  int tid = threadIdx.x;
  int i = blockIdx.y;
  int n0 = blockIdx.x * 128;
  if (tid < 128) {
    int node = n0 + tid;
    idxL[tid] = (node < N_NODES) ? idxTab[(size_t)node * idxStride + idxOff + i] : 0;
  }
  int nq = tid & 31;   // nodes 4nq..4nq+3
  int jq = tid >> 5;   // j 4jq..4jq+3
  float acc[4][4];
#pragma unroll
  for (int m = 0; m < 4; m++)
#pragma unroll
    for (int j = 0; j < 4; j++) acc[m][j] = 0.f;
  const float4* f4 = (const float4*)feats;
  const float4* w4 = (const float4*)wKK;
  __syncthreads();
  for (int kc = 0; kc < D; kc += 32) {
    for (int q = tid; q < 1024; q += NT) {       // gather-stage A transposed
      int node = q & 127, kg = q >> 7;
      float4 val = f4[(size_t)idxL[node] * DQ + (kc >> 2) + kg];
      int kl = kg << 2;
      ATl[kl + 0][node] = val.x; ATl[kl + 1][node] = val.y;
      ATl[kl + 2][node] = val.z; ATl[kl + 3][node] = val.w;
    }
    for (int q = tid; q < K * 8; q += NT) {      // stage W_i transposed
      int j = q & (K - 1), kg = q / K;
      float4 val = w4[((size_t)i * K + j) * DQ + (kc >> 2) + kg];
      int kl = kg << 2;
      WTl[kl + 0][j] = val.x; WTl[kl + 1][j] = val.y;
      WTl[kl + 2][j] = val.z; WTl[kl + 3][j] = val.w;
    }
    __syncthreads();
#pragma unroll
    for (int k = 0; k < 32; k++) {
      float4 a = *(const float4*)&ATl[k][nq << 2];
      float4 w = *(const float4*)&WTl[k][jq << 2];
      float am[4] = {a.x, a.y, a.z, a.w};
      float wm[4] = {w.x, w.y, w.z, w.w};
#pragma unroll
      for (int m = 0; m < 4; m++)
#pragma unroll
        for (int j = 0; j < 4; j++) acc[m][j] = fmaf(am[m], wm[j], acc[m][j]);
    }
    __syncthreads();
  }
#pragma unroll
  for (int m = 0; m < 4; m++) {
    int node = n0 + (nq << 2) + m;
    if (node < N_NODES) {
      float4 o;
      o.x = acc[m][0] + bKK[i * K + (jq << 2) + 0];
      o.y = acc[m][1] + bKK[i * K + (jq << 2) + 1];
      o.z = acc[m][2] + bKK[i * K + (jq << 2) + 2];
      o.w = acc[m][3] + bKK[i * K + (jq << 2) + 3];
      ((float4*)multBuf)[((size_t)node * K + i) * JG + jq] = o;
    }
  }
}

// ---------------- softmax + coef + gather-combine ----------------
template <int K>
__global__ __launch_bounds__(256) void kvconv2(const float* __restrict__ feats,
    const int* __restrict__ idxTab, int idxStride, int idxOff,
    const float* __restrict__ multBuf, const float* __restrict__ wK1,
    const float* __restrict__ bK1p, float* __restrict__ hx, int tslot) {
  __shared__ float multL[8][K][K + 1];
  __shared__ float aL[8][K];
  __shared__ float coefL[8][K];
  __shared__ int idxL[8][K];
  int tid = threadIdx.x;
  int n0 = blockIdx.x * 8;
  for (int q = tid; q < 8 * K; q += 256) {
    int nn = q / K, j = q & (K - 1);
    int node = n0 + nn;
    idxL[nn][j] = (node < N_NODES) ? idxTab[(size_t)node * idxStride + idxOff + j] : 0;
  }
  for (int q = tid; q < 8 * K * K; q += 256) {
    int nn = q / (K * K);
    int rem = q - nn * K * K;
    int ii = rem / K;
    int j = rem & (K - 1);
    int node = n0 + nn;
    multL[nn][ii][j] = (node < N_NODES) ? multBuf[(size_t)node * K * K + rem] : 0.f;
  }
  __syncthreads();
  for (int q = tid; q < 8 * K; q += 256) {   // row max / exp / sum; a = wK1/sum
    int nn = q / K, ii = q & (K - 1);
    float mx = -1e30f;
    for (int j = 0; j < K; j++) mx = fmaxf(mx, multL[nn][ii][j]);
    float s = 0.f;
    for (int j = 0; j < K; j++) {
      float e = expf(multL[nn][ii][j] - mx);
      multL[nn][ii][j] = e;
      s += e;
    }
    aL[nn][ii] = wK1[ii] / s;
  }
  __syncthreads();
  for (int q = tid; q < 8 * K; q += 256) {   // coef[j] = sum_i a[i]*P[i][j]
    int nn = q / K, j = q & (K - 1);
    float cs = 0.f;
    for (int ii = 0; ii < K; ii++) cs = fmaf(aL[nn][ii], multL[nn][ii][j], cs);
    coefL[nn][j] = cs;
  }
  __syncthreads();
  {
    int nn = tid >> 5, dq = tid & 31;
    int node = n0 + nn;
    if (node < N_NODES) {
      float bk1 = bK1p[0];
      float4 accv = make_float4(bk1, bk1, bk1, bk1);
      const float4* f4 = (const float4*)feats;
      for (int j = 0; j < K; j++) {
        float cf = coefL[nn][j];
        float4 xv = f4[(size_t)idxL[nn][j] * DQ + dq];
        accv.x = fmaf(cf, xv.x, accv.x);
        accv.y = fmaf(cf, xv.y, accv.y);
        accv.z = fmaf(cf, xv.z, accv.z);
        accv.w = fmaf(cf, xv.w, accv.w);
      }
      ((float4*)hx)[((size_t)node * T_HE + tslot) * DQ + dq] = accv;
    }
  }
}

// ---------------- edge attention + fc ----------------
__global__ __launch_bounds__(256) void kfinal(const float* __restrict__ hx,
    const float* __restrict__ w1, const float* __restrict__ b1,
    const float* __restrict__ w2, const float* __restrict__ b2p,
    const float* __restrict__ fcw, const float* __restrict__ fcb,
    float* __restrict__ out) {
  __shared__ float xL[8][T_HE][D];
  __shared__ float hL[8][T_HE][HID_SZ];
  __shared__ float scL[8][T_HE];
  __shared__ float aggL[8][D];
  int tid = threadIdx.x;
  int n0 = blockIdx.x * 8;
  const float4* hx4 = (const float4*)hx;
  for (int q = tid; q < 8 * T_HE * DQ; q += 256) {
    int nn = q / (T_HE * DQ);
    int rem = q - nn * (T_HE * DQ);
    int t = rem / DQ;
    int dq = rem & 31;
    int node = n0 + nn;
    float4 val = make_float4(0.f, 0.f, 0.f, 0.f);
    if (node < N_NODES) val = hx4[((size_t)node * T_HE + t) * DQ + dq];
    *(float4*)&xL[nn][t][dq << 2] = val;
  }
  __syncthreads();
  for (int q = tid; q < 8 * T_HE * HID_SZ; q += 256) {
    int nn = q / (T_HE * HID_SZ);
    int rem = q - nn * (T_HE * HID_SZ);
    int t = rem / HID_SZ;
    int hh = rem & (HID_SZ - 1);
    float acc = b1[hh];
    for (int d = 0; d < D; d++) acc = fmaf(xL[nn][t][d], w1[d * HID_SZ + hh], acc);
    hL[nn][t][hh] = fmaxf(acc, 0.f);
  }
  __syncthreads();
  if (tid < 8 * T_HE) {
    int nn = tid / T_HE, t = tid % T_HE;
    float acc = b2p[0];
    for (int hh = 0; hh < HID_SZ; hh++) acc = fmaf(hL[nn][t][hh], w2[hh], acc);
    scL[nn][t] = acc;
  }
  __syncthreads();
  if (tid < 8) {
    float mx = -1e30f;
#pragma unroll
    for (int t = 0; t < T_HE; t++) mx = fmaxf(mx, scL[tid][t]);
    float e[T_HE];
    float s = 0.f;
#pragma unroll
    for (int t = 0; t < T_HE; t++) { e[t] = expf(scL[tid][t] - mx); s += e[t]; }
    float inv = 1.f / s;
#pragma unroll
    for (int t = 0; t < T_HE; t++) scL[tid][t] = e[t] * inv;
  }
  __syncthreads();
  {
    int nn = tid >> 5, dq = tid & 31;
    float4 acc = make_float4(0.f, 0.f, 0.f, 0.f);
#pragma unroll
    for (int t = 0; t < T_HE; t++) {
      float sw = scL[nn][t];
      float4 xv = *(const float4*)&xL[nn][t][dq << 2];
      acc.x = fmaf(sw, xv.x, acc.x);
      acc.y = fmaf(sw, xv.y, acc.y);
      acc.z = fmaf(sw, xv.z, acc.z);
      acc.w = fmaf(sw, xv.w, acc.w);
    }
    *(float4*)&aggL[nn][dq << 2] = acc;
  }
  __syncthreads();
  {
    int dout = tid & 127, g = tid >> 7;
    float a0 = fcb[dout], a1 = a0, a2 = a0, a3 = a0;
    for (int d = 0; d < D; d++) {
      float w = fcw[d * 128 + dout];
      a0 = fmaf(aggL[g * 4 + 0][d], w, a0);
      a1 = fmaf(aggL[g * 4 + 1][d], w, a1);
      a2 = fmaf(aggL[g * 4 + 2][d], w, a2);
      a3 = fmaf(aggL[g * 4 + 3][d], w, a3);
    }
    int nb = n0 + g * 4;
    if (nb + 0 < N_NODES) out[(size_t)(nb + 0) * 128 + dout] = fmaxf(a0, 0.f);
    if (nb + 1 < N_NODES) out[(size_t)(nb + 1) * 128 + dout] = fmaxf(a1, 0.f);
    if (nb + 2 < N_NODES) out[(size_t)(nb + 2) * 128 + dout] = fmaxf(a2, 0.f);
    if (nb + 3 < N_NODES) out[(size_t)(nb + 3) * 128 + dout] = fmaxf(a3, 0.f);
  }
}

extern "C" void kernel_launch(void* const* d_in, const int* in_sizes, int n_in,
                              void* d_out, int out_size, void* d_ws, size_t ws_size,
                              hipStream_t stream) {
  (void)in_sizes; (void)n_in; (void)out_size; (void)ws_size;
  const float* feats       = (const float*)d_in[1];
  const int*   cluster_idx = (const int*)d_in[2];
  const int*   struct_idx  = (const int*)d_in[3];
  const float* wKK_c = (const float*)d_in[5];
  const float* bKK_c = (const float*)d_in[6];
  const float* wK1_c = (const float*)d_in[7];
  const float* bK1_c = (const float*)d_in[8];
  const float* wKK_n = (const float*)d_in[9];
  const float* bKK_n = (const float*)d_in[10];
  const float* wK1_n = (const float*)d_in[11];
  const float* bK1_n = (const float*)d_in[12];
  const float* wKK_s = (const float*)d_in[13];
  const float* bKK_s = (const float*)d_in[14];
  const float* wK1_s = (const float*)d_in[15];
  const float* bK1_s = (const float*)d_in[16];
  const float* ec_w1 = (const float*)d_in[17];
  const float* ec_b1 = (const float*)d_in[18];
  const float* ec_w2 = (const float*)d_in[19];
  const float* ec_b2 = (const float*)d_in[20];
  const float* fc_w  = (const float*)d_in[21];
  const float* fc_b  = (const float*)d_in[22];
  float* out = (float*)d_out;

  // ws layout (lifetime-overlapped): total 72.32 MB
  //  [0, 5.12M)        xn (f32)        dead after ksimtopk
  //  [5.12M, 25.6M)    cand (u64)      dead after kmerge
  //  [25.6M, 26.88M)   candIdx (int)   dead after krerank
  //  [26.88M, 26.96M)  normD (f64)     dead after krerank
  //  [0, 40.96M)       mult (f32)      written after krerank (overlaps the above)
  //  [46.08M, 46.72M)  knn (int)
  //  [46.72M, 72.32M)  hx (f32)
  char* wsb = (char*)d_ws;
  float* xn = (float*)(wsb);
  unsigned long long* cand = (unsigned long long*)(wsb + 5120000);
  int* candIdx = (int*)(wsb + 25600000);
  double* normD = (double*)(wsb + 26880000);
  float* mult = (float*)(wsb);
  int* knnIdx = (int*)(wsb + 46080000);
  float* hx = (float*)(wsb + 46720000);

  knorm<<<N_NODES, 64, 0, stream>>>(feats, xn, normD);
  ksimtopk<<<dim3(79, NCH), 256, 0, stream>>>(xn, cand);
  kmerge<<<(N_NODES + 255) / 256, 256, 0, stream>>>(cand, candIdx);
  krerank<<<N_NODES, 256, 0, stream>>>(feats, normD, candIdx, knnIdx);

  for (int c = 0; c < NCB; c++) {
    kmult<16><<<dim3(79, 16), 128, 0, stream>>>(feats, cluster_idx, NCB * 16, c * 16,
                                                wKK_c, bKK_c, mult);
    kvconv2<16><<<1250, 256, 0, stream>>>(feats, cluster_idx, NCB * 16, c * 16,
                                          mult, wK1_c, bK1_c, hx, c);
  }
  kmult<16><<<dim3(79, 16), 128, 0, stream>>>(feats, knnIdx, 16, 0, wKK_n, bKK_n, mult);
  kvconv2<16><<<1250, 256, 0, stream>>>(feats, knnIdx, 16, 0, mult, wK1_n, bK1_n, hx, 3);
  kmult<32><<<dim3(79, 32), 256, 0, stream>>>(feats, struct_idx, 32, 0, wKK_s, bKK_s, mult);
  kvconv2<32><<<1250, 256, 0, stream>>>(feats, struct_idx, 32, 0, mult, wK1_s, bK1_s, hx, 4);

  kfinal<<<1250, 256, 0, stream>>>(hx, ec_w1, ec_b1, ec_w2, ec_b2, fc_w, fc_b, out);
}

// Round 3
// 929.514 us; speedup vs baseline: 3.8953x; 3.8953x over previous
//
#include <hip/hip_runtime.h>
#include <cmath>

// DHGLayer on MI355X. N=10000, D=128.
// knorm (bf16 xnh + f64 norms) -> ksim (bf16 MFMA sim + branchless packed-u32
// per-chunk top-16) -> kmerge (global top-32 candidates) -> krerank (f64 exact
// top-16) -> kmult16x4 + kvconv16x4 (4 batched K=16 branches) -> kmult<32> +
// kvconv2<32> (struct) -> kfinal.
// Vertex conv collapsed: out = sum_j coef[j]*x[j,:], coef[j] = sum_i
// wK1[i]*softmax_row_i(mult)[j].
// Candidate gen may be sloppy (bf16 + 22-bit quantized keys): f64 rerank of the
// top-32 superset restores exactness (rank-16..32 gap ~0.017 >> bf16 noise 1.4e-4).

#define N_NODES 10000
#define D 128
#define DQ 32
#define NCB 3
#define T_HE 5
#define HID_SZ 32
#define NCH 16
#define CHUNK 625      // 16 * 625 = 10000
#define TOPK 16
#define TOPM 32

typedef __attribute__((ext_vector_type(8))) short short8;
typedef __attribute__((ext_vector_type(16))) float f32x16;

// ---------------- normalize -> bf16 xnh + f64 norm ----------------
__device__ __forceinline__ unsigned bf16rne(float f) {
  unsigned u = __float_as_uint(f);
  return (u + 0x7FFFu + ((u >> 16) & 1u)) >> 16;
}

__global__ __launch_bounds__(64) void knorm(const float* __restrict__ feats,
                                            unsigned short* __restrict__ xnh,
                                            double* __restrict__ normD) {
  int n = blockIdx.x;
  int lane = threadIdx.x;
  float2 v = ((const float2*)(feats + (size_t)n * D))[lane];
  double ss = (double)v.x * (double)v.x + (double)v.y * (double)v.y;
#pragma unroll
  for (int o = 32; o > 0; o >>= 1) ss += __shfl_xor(ss, o);
  double nd = fmax(sqrt(ss), 1e-12);
  if (lane == 0) normD[n] = nd;
  float inv = (float)(1.0 / nd);
  unsigned pa = bf16rne(v.x * inv), pb = bf16rne(v.y * inv);
  ((unsigned*)(xnh + (size_t)n * D))[lane] = pa | (pb << 16);
}

// ---------------- sorting-network helpers (u32, ascending) ----------------
__device__ __forceinline__ void ceu(unsigned& a, unsigned& b) {
  unsigned lo = min(a, b), hi = max(a, b);
  a = lo; b = hi;
}
__device__ __forceinline__ void sort16_asc(unsigned (&v)[16]) {
#pragma unroll
  for (int k = 2; k <= 16; k <<= 1) {
#pragma unroll
    for (int j = k >> 1; j > 0; j >>= 1) {
#pragma unroll
      for (int i = 0; i < 16; i++) {
        int x = i ^ j;
        if (x > i) {
          if ((i & k) == 0) ceu(v[i], v[x]);
          else ceu(v[x], v[i]);
        }
      }
    }
  }
}
// run ASC, b ASC -> run = top-16 of union, ASC (bitonic half-clean + merge)
__device__ __forceinline__ void merge16_asc(unsigned (&run)[16], const unsigned (&b)[16]) {
  unsigned m[16];
#pragma unroll
  for (int i = 0; i < 16; i++) m[i] = max(run[i], b[15 - i]);
#pragma unroll
  for (int j = 8; j > 0; j >>= 1) {
#pragma unroll
    for (int i = 0; i < 16; i++) {
      if ((i & j) == 0) ceu(m[i], m[i + j]);
    }
  }
#pragma unroll
  for (int i = 0; i < 16; i++) run[i] = m[i];
}

// ---------------- bf16 MFMA sim + per-chunk top-16 ----------------
// grid (79 row-blocks of 128, 16 chunks of 625 cols). 256 threads = 4 waves,
// waves 2x2 over the 128x128 tile. A-frags persistent in regs; B k-major in LDS
// (conflict-free b128); keys packed u32 = (val22 | (1023-colInChunk)); scan is
// branchless bitonic sort16+merge16 per thread (2 threads/row), XOR-swizzled
// key buffer to break 8-way LDS read conflicts.
__global__ __launch_bounds__(256, 2) void ksim(const unsigned short* __restrict__ xnh,
                                               unsigned* __restrict__ cand) {
  __shared__ short Bb[16 * 128 * 8];     // [kp][ci][8bf16] = 32 KB
  __shared__ unsigned keybuf[128 * 68];  // 34.8 KB (one 64-col half at a time)
  int tid = threadIdx.x;
  int row0 = blockIdx.x * 128;
  int chunk = blockIdx.y;
  int cbase = chunk * CHUNK;
  int w = tid >> 6, lane = tid & 63, l31 = lane & 31, lh = lane >> 5;
  int wrow = (w >> 1) * 64, wcol = (w & 1) * 64;

  // persistent A fragments: afr[mi][ks] = xnh[row][ks*16 + 8*lh .. +8]
  short8 afr[2][8];
#pragma unroll
  for (int mi = 0; mi < 2; mi++) {
    int ar = min(row0 + wrow + mi * 32 + l31, N_NODES - 1);
    const short8* ap = (const short8*)(xnh + (size_t)ar * D);
#pragma unroll
    for (int ks = 0; ks < 8; ks++) afr[mi][ks] = ap[ks * 2 + lh];
  }

  unsigned run[16];
#pragma unroll
  for (int s = 0; s < 16; s++) run[s] = 0u;
  int srow = tid & 127, sub = tid >> 7;
  unsigned swz = (unsigned)(((srow >> 3) & 7) << 3);

  for (int ti = 0; ti < 5; ti++) {
    int tb = cbase + ti * 128;
    {  // stage B (cols tb..tb+127), k-major
      int ci = tid >> 1, h = tid & 1;
      int gcol = min(tb + ci, N_NODES - 1);
      const short8* gp = (const short8*)(xnh + (size_t)gcol * D);
      short8* bp = (short8*)Bb;
#pragma unroll
      for (int i = 0; i < 8; i++) bp[(h * 8 + i) * 128 + ci] = gp[h * 8 + i];
    }
    __syncthreads();

    f32x16 acc[2][2];
#pragma unroll
    for (int mi = 0; mi < 2; mi++)
#pragma unroll
      for (int ni = 0; ni < 2; ni++)
#pragma unroll
        for (int r = 0; r < 16; r++) acc[mi][ni][r] = 0.f;

    const short8* bv = (const short8*)Bb;
#pragma unroll
    for (int ks = 0; ks < 8; ks++) {
      int kp = ks * 2 + lh;
      short8 b0 = bv[kp * 128 + wcol + l31];
      short8 b1 = bv[kp * 128 + wcol + 32 + l31];
#pragma unroll
      for (int mi = 0; mi < 2; mi++) {
        acc[mi][0] = __builtin_amdgcn_mfma_f32_32x32x16_bf16(afr[mi][ks], b0, acc[mi][0], 0, 0, 0);
        acc[mi][1] = __builtin_amdgcn_mfma_f32_32x32x16_bf16(afr[mi][ks], b1, acc[mi][1], 0, 0, 0);
      }
    }

    // two 64-col halves: write packed keys -> scan
#pragma unroll
    for (int hf = 0; hf < 2; hf++) {
      if ((w & 1) == hf) {
#pragma unroll
        for (int mi = 0; mi < 2; mi++)
#pragma unroll
          for (int ni = 0; ni < 2; ni++)
#pragma unroll
            for (int reg = 0; reg < 16; reg++) {
              int rl = wrow + mi * 32 + (reg & 3) + 8 * (reg >> 2) + 4 * lh;
              int chf = ni * 32 + l31;
              int cic = ti * 128 + hf * 64 + chf;
              float v = acc[mi][ni][reg];
              unsigned bb = __float_as_uint(v);
              unsigned mu = (bb & 0x80000000u) ? ~bb : (bb | 0x80000000u);
              unsigned key = (cic < CHUNK) ? ((mu & 0xFFFFFC00u) | (unsigned)(1023 - cic)) : 0u;
              unsigned sw = (unsigned)(((rl >> 3) & 7) << 3);
              keybuf[rl * 68 + ((unsigned)chf ^ sw)] = key;
            }
      }
      __syncthreads();
      {  // branchless scan: 2 batches of 16 cols per (row, sub)
        const unsigned* rowp = &keybuf[srow * 68];
#pragma unroll
        for (int bb2 = 0; bb2 < 2; bb2++) {
          unsigned bt[16];
#pragma unroll
          for (int q = 0; q < 4; q++) {
            unsigned off = ((unsigned)(sub * 32 + bb2 * 16 + q * 4)) ^ swz;
            uint4 t4 = *(const uint4*)(rowp + off);
            bt[q * 4 + 0] = t4.x; bt[q * 4 + 1] = t4.y;
            bt[q * 4 + 2] = t4.z; bt[q * 4 + 3] = t4.w;
          }
          sort16_asc(bt);
          merge16_asc(run, bt);
        }
      }
      __syncthreads();
    }
  }

  // cross-sub merge -> 16 chunk candidates per row
  if (sub == 1) {
#pragma unroll
    for (int s = 0; s < 16; s++) keybuf[srow * 68 + s] = run[s];
  }
  __syncthreads();
  if (sub == 0 && row0 + srow < N_NODES) {
    unsigned bl[16];
#pragma unroll
    for (int s = 0; s < 16; s++) bl[s] = keybuf[srow * 68 + s];
    merge16_asc(run, bl);
    unsigned* o = cand + ((size_t)(row0 + srow) * NCH + chunk) * 16;
#pragma unroll
    for (int i = 0; i < 16; i += 4)
      *(uint4*)(o + i) = make_uint4(run[i], run[i + 1], run[i + 2], run[i + 3]);
  }
}

// ---------------- merge chunk keys -> top-32 candidate cols ----------------
template <int S>
__device__ __forceinline__ void topk_insert(unsigned long long (&keys)[S],
                                            unsigned long long& thresh,
                                            unsigned long long key) {
  int mslot = 0;
  unsigned long long mk = keys[0];
#pragma unroll
  for (int s = 1; s < S; s++) { if (keys[s] < mk) { mk = keys[s]; mslot = s; } }
#pragma unroll
  for (int s = 0; s < S; s++) { if (s == mslot) keys[s] = key; }
  unsigned long long t2 = keys[0];
#pragma unroll
  for (int s = 1; s < S; s++) t2 = (keys[s] < t2) ? keys[s] : t2;
  thresh = t2;
}

__global__ __launch_bounds__(256) void kmerge(const unsigned* __restrict__ cand,
                                              int* __restrict__ candIdx) {
  int row = blockIdx.x * 256 + threadIdx.x;
  if (row >= N_NODES) return;
  unsigned long long keys[TOPM];
#pragma unroll
  for (int s = 0; s < TOPM; s++) keys[s] = 0ull;
  unsigned long long thresh = 0ull;
  const unsigned* c = cand + (size_t)row * (NCH * 16);
  for (int s = 0; s < NCH * 16; s++) {
    unsigned k = c[s];
    if (k == 0u) continue;
    unsigned cic = 1023u - (k & 1023u);
    unsigned gcol = (unsigned)((s >> 4) * CHUNK) + cic;
    unsigned long long k64 = ((unsigned long long)(k >> 10) << 32) | (unsigned)(~gcol);
    if (k64 > thresh) topk_insert<TOPM>(keys, thresh, k64);
  }
#pragma unroll
  for (int s = 0; s < TOPM; s++)
    candIdx[(size_t)row * TOPM + s] = (int)(~(unsigned)(keys[s] & 0xFFFFFFFFull));
}

// ---------------- f64 exact re-rank of 32 candidates -> knn top-16 ----------------
__global__ __launch_bounds__(256) void krerank(const float* __restrict__ feats,
                                               const double* __restrict__ normD,
                                               const int* __restrict__ candIdx,
                                               int* __restrict__ knn) {
  __shared__ float rowF[D];
  __shared__ double simL[TOPM];
  __shared__ int idxL[TOPM];
  int row = blockIdx.x;
  int tid = threadIdx.x;
  if (tid < DQ)
    ((float4*)rowF)[tid] = ((const float4*)(feats + (size_t)row * D))[tid];
  int c = tid >> 3, part = tid & 7;
  int cnd = candIdx[(size_t)row * TOPM + c];
  __syncthreads();
  const float4* f4 = (const float4*)(feats + (size_t)cnd * D);
  double acc = 0.0;
#pragma unroll
  for (int g = 0; g < 4; g++) {
    float4 v = f4[part * 4 + g];
    const float* rf = &rowF[(part * 4 + g) * 4];
    acc = fma((double)v.x, (double)rf[0], acc);
    acc = fma((double)v.y, (double)rf[1], acc);
    acc = fma((double)v.z, (double)rf[2], acc);
    acc = fma((double)v.w, (double)rf[3], acc);
  }
  acc += __shfl_down(acc, 4);
  acc += __shfl_down(acc, 2);
  acc += __shfl_down(acc, 1);
  if (part == 0) {
    simL[c] = acc / (normD[row] * normD[cnd]);
    idxL[c] = cnd;
  }
  __syncthreads();
  if (tid < TOPM) {
    double s = simL[tid];
    int idx = idxL[tid];
    int rank = 0;
#pragma unroll
    for (int o = 0; o < TOPM; o++) {
      double so = simL[o];
      int io = idxL[o];
      rank += (so > s || (so == s && io < idx)) ? 1 : 0;
    }
    if (rank < TOPK) knn[(size_t)row * TOPK + rank] = idx;
  }
}

// ---------------- mult GEMM (batched, K=16, 4 branches via blockIdx.z) ----------------
__global__ __launch_bounds__(128) void kmult16x4(const float* __restrict__ feats,
    const int* __restrict__ cluster_idx, const int* __restrict__ knn,
    const float* __restrict__ wKK_c, const float* __restrict__ bKK_c,
    const float* __restrict__ wKK_n, const float* __restrict__ bKK_n,
    float* __restrict__ mult) {
  const int K = 16, NT = 128;
  __shared__ float ATl[32][132];
  __shared__ float WTl[32][K + 4];
  __shared__ int idxL[128];
  int z = blockIdx.z;
  const int* idxTab; int idxStride, idxOff;
  const float* wKK; const float* bKK;
  if (z < 3) { idxTab = cluster_idx; idxStride = NCB * 16; idxOff = z * 16; wKK = wKK_c; bKK = bKK_c; }
  else       { idxTab = knn;         idxStride = 16;       idxOff = 0;      wKK = wKK_n; bKK = bKK_n; }
  float* multBuf = mult + (size_t)z * 2560000;
  int tid = threadIdx.x;
  int i = blockIdx.y;
  int n0 = blockIdx.x * 128;
  if (tid < 128) {
    int node = n0 + tid;
    idxL[tid] = (node < N_NODES) ? idxTab[(size_t)node * idxStride + idxOff + i] : 0;
  }
  int nq = tid & 31, jq = tid >> 5;
  float acc[4][4];
#pragma unroll
  for (int m = 0; m < 4; m++)
#pragma unroll
    for (int j = 0; j < 4; j++) acc[m][j] = 0.f;
  const float4* f4 = (const float4*)feats;
  const float4* w4 = (const float4*)wKK;
  __syncthreads();
  for (int kc = 0; kc < D; kc += 32) {
    for (int q = tid; q < 1024; q += NT) {
      int node = q & 127, kg = q >> 7;
      float4 val = f4[(size_t)idxL[node] * DQ + (kc >> 2) + kg];
      int kl = kg << 2;
      ATl[kl + 0][node] = val.x; ATl[kl + 1][node] = val.y;
      ATl[kl + 2][node] = val.z; ATl[kl + 3][node] = val.w;
    }
    for (int q = tid; q < K * 8; q += NT) {
      int j = q & (K - 1), kg = q / K;
      float4 val = w4[((size_t)i * K + j) * DQ + (kc >> 2) + kg];
      int kl = kg << 2;
      WTl[kl + 0][j] = val.x; WTl[kl + 1][j] = val.y;
      WTl[kl + 2][j] = val.z; WTl[kl + 3][j] = val.w;
    }
    __syncthreads();
#pragma unroll
    for (int k = 0; k < 32; k++) {
      float4 a = *(const float4*)&ATl[k][nq << 2];
      float4 wv = *(const float4*)&WTl[k][jq << 2];
      float am[4] = {a.x, a.y, a.z, a.w};
      float wm[4] = {wv.x, wv.y, wv.z, wv.w};
#pragma unroll
      for (int m = 0; m < 4; m++)
#pragma unroll
        for (int j = 0; j < 4; j++) acc[m][j] = fmaf(am[m], wm[j], acc[m][j]);
    }
    __syncthreads();
  }
#pragma unroll
  for (int m = 0; m < 4; m++) {
    int node = n0 + (nq << 2) + m;
    if (node < N_NODES) {
      float4 o;
      o.x = acc[m][0] + bKK[i * K + (jq << 2) + 0];
      o.y = acc[m][1] + bKK[i * K + (jq << 2) + 1];
      o.z = acc[m][2] + bKK[i * K + (jq << 2) + 2];
      o.w = acc[m][3] + bKK[i * K + (jq << 2) + 3];
      ((float4*)multBuf)[((size_t)node * K + i) * (K / 4) + jq] = o;
    }
  }
}

// ---------------- mult GEMM (K=32, struct) ----------------
template <int K>
__global__ __launch_bounds__(256) void kmult(const float* __restrict__ feats,
    const int* __restrict__ idxTab, int idxStride, int idxOff,
    const float* __restrict__ wKK, const float* __restrict__ bKK,
    float* __restrict__ multBuf) {
  constexpr int NT = 8 * K;
  constexpr int JG = K / 4;
  __shared__ float ATl[32][132];
  __shared__ float WTl[32][K + 4];
  __shared__ int idxL[128];
  int tid = threadIdx.x;
  int i = blockIdx.y;
  int n0 = blockIdx.x * 128;
  if (tid < 128) {
    int node = n0 + tid;
    idxL[tid] = (node < N_NODES) ? idxTab[(size_t)node * idxStride + idxOff + i] : 0;
  }
  int nq = tid & 31, jq = tid >> 5;
  float acc[4][4];
#pragma unroll
  for (int m = 0; m < 4; m++)
#pragma unroll
    for (int j = 0; j < 4; j++) acc[m][j] = 0.f;
  const float4* f4 = (const float4*)feats;
  const float4* w4 = (const float4*)wKK;
  __syncthreads();
  for (int kc = 0; kc < D; kc += 32) {
    for (int q = tid; q < 1024; q += NT) {
      int node = q & 127, kg = q >> 7;
      float4 val = f4[(size_t)idxL[node] * DQ + (kc >> 2) + kg];
      int kl = kg << 2;
      ATl[kl + 0][node] = val.x; ATl[kl + 1][node] = val.y;
      ATl[kl + 2][node] = val.z; ATl[kl + 3][node] = val.w;
    }
    for (int q = tid; q < K * 8; q += NT) {
      int j = q & (K - 1), kg = q / K;
      float4 val = w4[((size_t)i * K + j) * DQ + (kc >> 2) + kg];
      int kl = kg << 2;
      WTl[kl + 0][j] = val.x; WTl[kl + 1][j] = val.y;
      WTl[kl + 2][j] = val.z; WTl[kl + 3][j] = val.w;
    }
    __syncthreads();
#pragma unroll
    for (int k = 0; k < 32; k++) {
      float4 a = *(const float4*)&ATl[k][nq << 2];
      float4 wv = *(const float4*)&WTl[k][jq << 2];
      float am[4] = {a.x, a.y, a.z, a.w};
      float wm[4] = {wv.x, wv.y, wv.z, wv.w};
#pragma unroll
      for (int m = 0; m < 4; m++)
#pragma unroll
        for (int j = 0; j < 4; j++) acc[m][j] = fmaf(am[m], wm[j], acc[m][j]);
    }
    __syncthreads();
  }
#pragma unroll
  for (int m = 0; m < 4; m++) {
    int node = n0 + (nq << 2) + m;
    if (node < N_NODES) {
      float4 o;
      o.x = acc[m][0] + bKK[i * K + (jq << 2) + 0];
      o.y = acc[m][1] + bKK[i * K + (jq << 2) + 1];
      o.z = acc[m][2] + bKK[i * K + (jq << 2) + 2];
      o.w = acc[m][3] + bKK[i * K + (jq << 2) + 3];
      ((float4*)multBuf)[((size_t)node * K + i) * JG + jq] = o;
    }
  }
}

// ---------------- softmax + coef + gather-combine (batched K=16) ----------------
__global__ __launch_bounds__(256) void kvconv16x4(const float* __restrict__ feats,
    const int* __restrict__ cluster_idx, const int* __restrict__ knn,
    const float* __restrict__ mult,
    const float* __restrict__ wK1_c, const float* __restrict__ bK1_c,
    const float* __restrict__ wK1_n, const float* __restrict__ bK1_n,
    float* __restrict__ hx) {
  const int K = 16;
  __shared__ float multL[8][K][K + 1];
  __shared__ float aL[8][K];
  __shared__ float coefL[8][K];
  __shared__ int idxL[8][K];
  int z = blockIdx.y;
  const int* idxTab; int idxStride, idxOff;
  const float* wK1; const float* bK1p;
  if (z < 3) { idxTab = cluster_idx; idxStride = NCB * 16; idxOff = z * 16; wK1 = wK1_c; bK1p = bK1_c; }
  else       { idxTab = knn;         idxStride = 16;       idxOff = 0;      wK1 = wK1_n; bK1p = bK1_n; }
  const float* multBuf = mult + (size_t)z * 2560000;
  int tslot = z;
  int tid = threadIdx.x;
  int n0 = blockIdx.x * 8;
  for (int q = tid; q < 8 * K; q += 256) {
    int nn = q / K, j = q & (K - 1);
    int node = n0 + nn;
    idxL[nn][j] = (node < N_NODES) ? idxTab[(size_t)node * idxStride + idxOff + j] : 0;
  }
  for (int q = tid; q < 8 * K * K; q += 256) {
    int nn = q / (K * K);
    int rem = q - nn * K * K;
    int node = n0 + nn;
    multL[nn][rem / K][rem & (K - 1)] = (node < N_NODES) ? multBuf[(size_t)node * K * K + rem] : 0.f;
  }
  __syncthreads();
  for (int q = tid; q < 8 * K; q += 256) {
    int nn = q / K, ii = q & (K - 1);
    float mx = -1e30f;
    for (int j = 0; j < K; j++) mx = fmaxf(mx, multL[nn][ii][j]);
    float s = 0.f;
    for (int j = 0; j < K; j++) {
      float e = expf(multL[nn][ii][j] - mx);
      multL[nn][ii][j] = e;
      s += e;
    }
    aL[nn][ii] = wK1[ii] / s;
  }
  __syncthreads();
  for (int q = tid; q < 8 * K; q += 256) {
    int nn = q / K, j = q & (K - 1);
    float cs = 0.f;
    for (int ii = 0; ii < K; ii++) cs = fmaf(aL[nn][ii], multL[nn][ii][j], cs);
    coefL[nn][j] = cs;
  }
  __syncthreads();
  {
    int nn = tid >> 5, dq = tid & 31;
    int node = n0 + nn;
    if (node < N_NODES) {
      float bk1 = bK1p[0];
      float4 accv = make_float4(bk1, bk1, bk1, bk1);
      const float4* f4 = (const float4*)feats;
      for (int j = 0; j < K; j++) {
        float cf = coefL[nn][j];
        float4 xv = f4[(size_t)idxL[nn][j] * DQ + dq];
        accv.x = fmaf(cf, xv.x, accv.x);
        accv.y = fmaf(cf, xv.y, accv.y);
        accv.z = fmaf(cf, xv.z, accv.z);
        accv.w = fmaf(cf, xv.w, accv.w);
      }
      ((float4*)hx)[((size_t)node * T_HE + tslot) * DQ + dq] = accv;
    }
  }
}

// ---------------- softmax + coef + gather-combine (K=32, struct) ----------------
template <int K>
__global__ __launch_bounds__(256) void kvconv2(const float* __restrict__ feats,
    const int* __restrict__ idxTab, int idxStride, int idxOff,
    const float* __restrict__ multBuf, const float* __restrict__ wK1,
    const float* __restrict__ bK1p, float* __restrict__ hx, int tslot) {
  __shared__ float multL[8][K][K + 1];
  __shared__ float aL[8][K];
  __shared__ float coefL[8][K];
  __shared__ int idxL[8][K];
  int tid = threadIdx.x;
  int n0 = blockIdx.x * 8;
  for (int q = tid; q < 8 * K; q += 256) {
    int nn = q / K, j = q & (K - 1);
    int node = n0 + nn;
    idxL[nn][j] = (node < N_NODES) ? idxTab[(size_t)node * idxStride + idxOff + j] : 0;
  }
  for (int q = tid; q < 8 * K * K; q += 256) {
    int nn = q / (K * K);
    int rem = q - nn * K * K;
    int node = n0 + nn;
    multL[nn][rem / K][rem & (K - 1)] = (node < N_NODES) ? multBuf[(size_t)node * K * K + rem] : 0.f;
  }
  __syncthreads();
  for (int q = tid; q < 8 * K; q += 256) {
    int nn = q / K, ii = q & (K - 1);
    float mx = -1e30f;
    for (int j = 0; j < K; j++) mx = fmaxf(mx, multL[nn][ii][j]);
    float s = 0.f;
    for (int j = 0; j < K; j++) {
      float e = expf(multL[nn][ii][j] - mx);
      multL[nn][ii][j] = e;
      s += e;
    }
    aL[nn][ii] = wK1[ii] / s;
  }
  __syncthreads();
  for (int q = tid; q < 8 * K; q += 256) {
    int nn = q / K, j = q & (K - 1);
    float cs = 0.f;
    for (int ii = 0; ii < K; ii++) cs = fmaf(aL[nn][ii], multL[nn][ii][j], cs);
    coefL[nn][j] = cs;
  }
  __syncthreads();
  {
    int nn = tid >> 5, dq = tid & 31;
    int node = n0 + nn;
    if (node < N_NODES) {
      float bk1 = bK1p[0];
      float4 accv = make_float4(bk1, bk1, bk1, bk1);
      const float4* f4 = (const float4*)feats;
      for (int j = 0; j < K; j++) {
        float cf = coefL[nn][j];
        float4 xv = f4[(size_t)idxL[nn][j] * DQ + dq];
        accv.x = fmaf(cf, xv.x, accv.x);
        accv.y = fmaf(cf, xv.y, accv.y);
        accv.z = fmaf(cf, xv.z, accv.z);
        accv.w = fmaf(cf, xv.w, accv.w);
      }
      ((float4*)hx)[((size_t)node * T_HE + tslot) * DQ + dq] = accv;
    }
  }
}

// ---------------- edge attention + fc ----------------
__global__ __launch_bounds__(256) void kfinal(const float* __restrict__ hx,
    const float* __restrict__ w1, const float* __restrict__ b1,
    const float* __restrict__ w2, const float* __restrict__ b2p,
    const float* __restrict__ fcw, const float* __restrict__ fcb,
    float* __restrict__ out) {
  __shared__ float xL[8][T_HE][D];
  __shared__ float hL[8][T_HE][HID_SZ];
  __shared__ float scL[8][T_HE];
  __shared__ float aggL[8][D];
  int tid = threadIdx.x;
  int n0 = blockIdx.x * 8;
  const float4* hx4 = (const float4*)hx;
  for (int q = tid; q < 8 * T_HE * DQ; q += 256) {
    int nn = q / (T_HE * DQ);
    int rem = q - nn * (T_HE * DQ);
    int t = rem / DQ;
    int dq = rem & 31;
    int node = n0 + nn;
    float4 val = make_float4(0.f, 0.f, 0.f, 0.f);
    if (node < N_NODES) val = hx4[((size_t)node * T_HE + t) * DQ + dq];
    *(float4*)&xL[nn][t][dq << 2] = val;
  }
  __syncthreads();
  for (int q = tid; q < 8 * T_HE * HID_SZ; q += 256) {
    int nn = q / (T_HE * HID_SZ);
    int rem = q - nn * (T_HE * HID_SZ);
    int t = rem / HID_SZ;
    int hh = rem & (HID_SZ - 1);
    float acc = b1[hh];
    for (int d = 0; d < D; d++) acc = fmaf(xL[nn][t][d], w1[d * HID_SZ + hh], acc);
    hL[nn][t][hh] = fmaxf(acc, 0.f);
  }
  __syncthreads();
  if (tid < 8 * T_HE) {
    int nn = tid / T_HE, t = tid % T_HE;
    float acc = b2p[0];
    for (int hh = 0; hh < HID_SZ; hh++) acc = fmaf(hL[nn][t][hh], w2[hh], acc);
    scL[nn][t] = acc;
  }
  __syncthreads();
  if (tid < 8) {
    float mx = -1e30f;
#pragma unroll
    for (int t = 0; t < T_HE; t++) mx = fmaxf(mx, scL[tid][t]);
    float e[T_HE];
    float s = 0.f;
#pragma unroll
    for (int t = 0; t < T_HE; t++) { e[t] = expf(scL[tid][t] - mx); s += e[t]; }
    float inv = 1.f / s;
#pragma unroll
    for (int t = 0; t < T_HE; t++) scL[tid][t] = e[t] * inv;
  }
  __syncthreads();
  {
    int nn = tid >> 5, dq = tid & 31;
    float4 acc = make_float4(0.f, 0.f, 0.f, 0.f);
#pragma unroll
    for (int t = 0; t < T_HE; t++) {
      float sw = scL[nn][t];
      float4 xv = *(const float4*)&xL[nn][t][dq << 2];
      acc.x = fmaf(sw, xv.x, acc.x);
      acc.y = fmaf(sw, xv.y, acc.y);
      acc.z = fmaf(sw, xv.z, acc.z);
      acc.w = fmaf(sw, xv.w, acc.w);
    }
    *(float4*)&aggL[nn][dq << 2] = acc;
  }
  __syncthreads();
  {
    int dout = tid & 127, g = tid >> 7;
    float a0 = fcb[dout], a1 = a0, a2 = a0, a3 = a0;
    for (int d = 0; d < D; d++) {
      float w = fcw[d * 128 + dout];
      a0 = fmaf(aggL[g * 4 + 0][d], w, a0);
      a1 = fmaf(aggL[g * 4 + 1][d], w, a1);
      a2 = fmaf(aggL[g * 4 + 2][d], w, a2);
      a3 = fmaf(aggL[g * 4 + 3][d], w, a3);
    }
    int nb = n0 + g * 4;
    if (nb + 0 < N_NODES) out[(size_t)(nb + 0) * 128 + dout] = fmaxf(a0, 0.f);
    if (nb + 1 < N_NODES) out[(size_t)(nb + 1) * 128 + dout] = fmaxf(a1, 0.f);
    if (nb + 2 < N_NODES) out[(size_t)(nb + 2) * 128 + dout] = fmaxf(a2, 0.f);
    if (nb + 3 < N_NODES) out[(size_t)(nb + 3) * 128 + dout] = fmaxf(a3, 0.f);
  }
}

extern "C" void kernel_launch(void* const* d_in, const int* in_sizes, int n_in,
                              void* d_out, int out_size, void* d_ws, size_t ws_size,
                              hipStream_t stream) {
  (void)in_sizes; (void)n_in; (void)out_size; (void)ws_size;
  const float* feats       = (const float*)d_in[1];
  const int*   cluster_idx = (const int*)d_in[2];
  const int*   struct_idx  = (const int*)d_in[3];
  const float* wKK_c = (const float*)d_in[5];
  const float* bKK_c = (const float*)d_in[6];
  const float* wK1_c = (const float*)d_in[7];
  const float* bK1_c = (const float*)d_in[8];
  const float* wKK_n = (const float*)d_in[9];
  const float* bKK_n = (const float*)d_in[10];
  const float* wK1_n = (const float*)d_in[11];
  const float* bK1_n = (const float*)d_in[12];
  const float* wKK_s = (const float*)d_in[13];
  const float* bKK_s = (const float*)d_in[14];
  const float* wK1_s = (const float*)d_in[15];
  const float* bK1_s = (const float*)d_in[16];
  const float* ec_w1 = (const float*)d_in[17];
  const float* ec_b1 = (const float*)d_in[18];
  const float* ec_w2 = (const float*)d_in[19];
  const float* ec_b2 = (const float*)d_in[20];
  const float* fc_w  = (const float*)d_in[21];
  const float* fc_b  = (const float*)d_in[22];
  float* out = (float*)d_out;

  // ws layout (lifetime-overlapped, total 72.32 MB — proven fits):
  //  [0, 2.56M)        xnh (bf16)     dead after ksim
  //  [2.56M, 12.8M)    cand (u32)     dead after kmerge
  //  [12.8M, 14.08M)   candIdx (int)  dead after krerank
  //  [14.08M, 14.16M)  normD (f64)    dead after krerank
  //  [0, 40.96M)       mult (f32)     written after krerank (4x2.56M floats K=16; reused for K=32)
  //  [46.08M, 46.72M)  knn (int)
  //  [46.72M, 72.32M)  hx (f32)
  char* wsb = (char*)d_ws;
  unsigned short* xnh = (unsigned short*)(wsb);
  unsigned* cand = (unsigned*)(wsb + 2560000);
  int* candIdx = (int*)(wsb + 12800000);
  double* normD = (double*)(wsb + 14080000);
  float* mult = (float*)(wsb);
  int* knnIdx = (int*)(wsb + 46080000);
  float* hx = (float*)(wsb + 46720000);

  knorm<<<N_NODES, 64, 0, stream>>>(feats, xnh, normD);
  ksim<<<dim3(79, NCH), 256, 0, stream>>>(xnh, cand);
  kmerge<<<(N_NODES + 255) / 256, 256, 0, stream>>>(cand, candIdx);
  krerank<<<N_NODES, 256, 0, stream>>>(feats, normD, candIdx, knnIdx);

  kmult16x4<<<dim3(79, 16, 4), 128, 0, stream>>>(feats, cluster_idx, knnIdx,
                                                 wKK_c, bKK_c, wKK_n, bKK_n, mult);
  kvconv16x4<<<dim3(1250, 4), 256, 0, stream>>>(feats, cluster_idx, knnIdx, mult,
                                                wK1_c, bK1_c, wK1_n, bK1_n, hx);
  kmult<32><<<dim3(79, 32), 256, 0, stream>>>(feats, struct_idx, 32, 0, wKK_s, bKK_s, mult);
  kvconv2<32><<<1250, 256, 0, stream>>>(feats, struct_idx, 32, 0, mult, wK1_s, bK1_s, hx, 4);

  kfinal<<<1250, 256, 0, stream>>>(hx, ec_w1, ec_b1, ec_w2, ec_b2, fc_w, fc_b, out);
}

// Round 4
// 540.513 us; speedup vs baseline: 6.6987x; 1.7197x over previous
//
#include <hip/hip_runtime.h>
#include <cmath>

// DHGLayer on MI355X. N=10000, D=128.
// knorm (bf16 xnh + f64 norms) -> ksim (bf16 MFMA sim + branchless packed-u32
// per-chunk top-16) -> kmerge (branchless bitonic merge of 16 sorted runs ->
// top-32 candidates) -> krerank (f64 exact top-16) -> kmult16x4 + kvconv16x4
// (4 batched K=16 branches) -> kmult<32> + kvconv2<32> (struct) -> kfinal.
// Vertex conv collapsed: out = sum_j coef[j]*x[j,:], coef[j] = sum_i
// wK1[i]*softmax_row_i(mult)[j].
// Candidate gen may be sloppy (bf16 + 22-bit quantized keys): f64 rerank of the
// top-32 superset restores exactness (rank-16..32 gap ~0.017 >> bf16 noise 1.4e-4).

#define N_NODES 10000
#define D 128
#define DQ 32
#define NCB 3
#define T_HE 5
#define HID_SZ 32
#define NCH 16
#define CHUNK 625      // 16 * 625 = 10000
#define TOPK 16
#define TOPM 32

typedef __attribute__((ext_vector_type(8))) short short8;
typedef __attribute__((ext_vector_type(16))) float f32x16;

// ---------------- normalize -> bf16 xnh + f64 norm ----------------
__device__ __forceinline__ unsigned bf16rne(float f) {
  unsigned u = __float_as_uint(f);
  return (u + 0x7FFFu + ((u >> 16) & 1u)) >> 16;
}

__global__ __launch_bounds__(64) void knorm(const float* __restrict__ feats,
                                            unsigned short* __restrict__ xnh,
                                            double* __restrict__ normD) {
  int n = blockIdx.x;
  int lane = threadIdx.x;
  float2 v = ((const float2*)(feats + (size_t)n * D))[lane];
  double ss = (double)v.x * (double)v.x + (double)v.y * (double)v.y;
#pragma unroll
  for (int o = 32; o > 0; o >>= 1) ss += __shfl_xor(ss, o);
  double nd = fmax(sqrt(ss), 1e-12);
  if (lane == 0) normD[n] = nd;
  float inv = (float)(1.0 / nd);
  unsigned pa = bf16rne(v.x * inv), pb = bf16rne(v.y * inv);
  ((unsigned*)(xnh + (size_t)n * D))[lane] = pa | (pb << 16);
}

// ---------------- sorting-network helpers ----------------
__device__ __forceinline__ void ceu(unsigned& a, unsigned& b) {
  unsigned lo = min(a, b), hi = max(a, b);
  a = lo; b = hi;
}
__device__ __forceinline__ void ceu64(unsigned long long& a, unsigned long long& b) {
  unsigned long long lo = min(a, b), hi = max(a, b);
  a = lo; b = hi;
}
__device__ __forceinline__ void sort16_asc(unsigned (&v)[16]) {
#pragma unroll
  for (int k = 2; k <= 16; k <<= 1) {
#pragma unroll
    for (int j = k >> 1; j > 0; j >>= 1) {
#pragma unroll
      for (int i = 0; i < 16; i++) {
        int x = i ^ j;
        if (x > i) {
          if ((i & k) == 0) ceu(v[i], v[x]);
          else ceu(v[x], v[i]);
        }
      }
    }
  }
}
// run ASC, b ASC -> run = top-16 of union, ASC (bitonic half-clean + merge)
__device__ __forceinline__ void merge16_asc(unsigned (&run)[16], const unsigned (&b)[16]) {
  unsigned m[16];
#pragma unroll
  for (int i = 0; i < 16; i++) m[i] = max(run[i], b[15 - i]);
#pragma unroll
  for (int j = 8; j > 0; j >>= 1) {
#pragma unroll
    for (int i = 0; i < 16; i++) {
      if ((i & j) == 0) ceu(m[i], m[i + j]);
    }
  }
#pragma unroll
  for (int i = 0; i < 16; i++) run[i] = m[i];
}

// ---------------- bf16 MFMA sim + per-chunk top-16 ----------------
// grid (79 row-blocks of 128, 16 chunks of 625 cols). 256 threads = 4 waves,
// waves 2x2 over the 128x128 tile. A-frags persistent in regs; B k-major in LDS
// (conflict-free b128); keys packed u32 = (val22 | (1023-colInChunk)); scan is
// branchless bitonic sort16+merge16 per thread (2 threads/row), XOR-swizzled
// key buffer to break 8-way LDS read conflicts.
__global__ __launch_bounds__(256, 2) void ksim(const unsigned short* __restrict__ xnh,
                                               unsigned* __restrict__ cand) {
  __shared__ short Bb[16 * 128 * 8];     // [kp][ci][8bf16] = 32 KB
  __shared__ unsigned keybuf[128 * 68];  // 34.8 KB (one 64-col half at a time)
  int tid = threadIdx.x;
  int row0 = blockIdx.x * 128;
  int chunk = blockIdx.y;
  int cbase = chunk * CHUNK;
  int w = tid >> 6, lane = tid & 63, l31 = lane & 31, lh = lane >> 5;
  int wrow = (w >> 1) * 64, wcol = (w & 1) * 64;

  // persistent A fragments: afr[mi][ks] = xnh[row][ks*16 + 8*lh .. +8]
  short8 afr[2][8];
#pragma unroll
  for (int mi = 0; mi < 2; mi++) {
    int ar = min(row0 + wrow + mi * 32 + l31, N_NODES - 1);
    const short8* ap = (const short8*)(xnh + (size_t)ar * D);
#pragma unroll
    for (int ks = 0; ks < 8; ks++) afr[mi][ks] = ap[ks * 2 + lh];
  }

  unsigned run[16];
#pragma unroll
  for (int s = 0; s < 16; s++) run[s] = 0u;
  int srow = tid & 127, sub = tid >> 7;
  unsigned swz = (unsigned)(((srow >> 3) & 7) << 3);

  for (int ti = 0; ti < 5; ti++) {
    int tb = cbase + ti * 128;
    {  // stage B (cols tb..tb+127), k-major
      int ci = tid >> 1, h = tid & 1;
      int gcol = min(tb + ci, N_NODES - 1);
      const short8* gp = (const short8*)(xnh + (size_t)gcol * D);
      short8* bp = (short8*)Bb;
#pragma unroll
      for (int i = 0; i < 8; i++) bp[(h * 8 + i) * 128 + ci] = gp[h * 8 + i];
    }
    __syncthreads();

    f32x16 acc[2][2];
#pragma unroll
    for (int mi = 0; mi < 2; mi++)
#pragma unroll
      for (int ni = 0; ni < 2; ni++)
#pragma unroll
        for (int r = 0; r < 16; r++) acc[mi][ni][r] = 0.f;

    const short8* bv = (const short8*)Bb;
#pragma unroll
    for (int ks = 0; ks < 8; ks++) {
      int kp = ks * 2 + lh;
      short8 b0 = bv[kp * 128 + wcol + l31];
      short8 b1 = bv[kp * 128 + wcol + 32 + l31];
#pragma unroll
      for (int mi = 0; mi < 2; mi++) {
        acc[mi][0] = __builtin_amdgcn_mfma_f32_32x32x16_bf16(afr[mi][ks], b0, acc[mi][0], 0, 0, 0);
        acc[mi][1] = __builtin_amdgcn_mfma_f32_32x32x16_bf16(afr[mi][ks], b1, acc[mi][1], 0, 0, 0);
      }
    }

    // two 64-col halves: write packed keys -> scan
#pragma unroll
    for (int hf = 0; hf < 2; hf++) {
      if ((w & 1) == hf) {
#pragma unroll
        for (int mi = 0; mi < 2; mi++)
#pragma unroll
          for (int ni = 0; ni < 2; ni++)
#pragma unroll
            for (int reg = 0; reg < 16; reg++) {
              int rl = wrow + mi * 32 + (reg & 3) + 8 * (reg >> 2) + 4 * lh;
              int chf = ni * 32 + l31;
              int cic = ti * 128 + hf * 64 + chf;
              float v = acc[mi][ni][reg];
              unsigned bb = __float_as_uint(v);
              unsigned mu = (bb & 0x80000000u) ? ~bb : (bb | 0x80000000u);
              unsigned key = (cic < CHUNK) ? ((mu & 0xFFFFFC00u) | (unsigned)(1023 - cic)) : 0u;
              unsigned sw = (unsigned)(((rl >> 3) & 7) << 3);
              keybuf[rl * 68 + ((unsigned)chf ^ sw)] = key;
            }
      }
      __syncthreads();
      {  // branchless scan: 2 batches of 16 cols per (row, sub)
        const unsigned* rowp = &keybuf[srow * 68];
#pragma unroll
        for (int bb2 = 0; bb2 < 2; bb2++) {
          unsigned bt[16];
#pragma unroll
          for (int q = 0; q < 4; q++) {
            unsigned off = ((unsigned)(sub * 32 + bb2 * 16 + q * 4)) ^ swz;
            uint4 t4 = *(const uint4*)(rowp + off);
            bt[q * 4 + 0] = t4.x; bt[q * 4 + 1] = t4.y;
            bt[q * 4 + 2] = t4.z; bt[q * 4 + 3] = t4.w;
          }
          sort16_asc(bt);
          merge16_asc(run, bt);
        }
      }
      __syncthreads();
    }
  }

  // cross-sub merge -> 16 chunk candidates per row
  if (sub == 1) {
#pragma unroll
    for (int s = 0; s < 16; s++) keybuf[srow * 68 + s] = run[s];
  }
  __syncthreads();
  if (sub == 0 && row0 + srow < N_NODES) {
    unsigned bl[16];
#pragma unroll
    for (int s = 0; s < 16; s++) bl[s] = keybuf[srow * 68 + s];
    merge16_asc(run, bl);
    unsigned* o = cand + ((size_t)(row0 + srow) * NCH + chunk) * 16;
#pragma unroll
    for (int i = 0; i < 16; i += 4)
      *(uint4*)(o + i) = make_uint4(run[i], run[i + 1], run[i + 2], run[i + 3]);
  }
}

// ---------------- merge chunk keys -> top-32 candidate cols ----------------
// One thread per row. Inputs are 16 sorted-ASC runs of 16 u32 keys. Maintain a
// sorted-ASC run[32] of u64 global keys; per chunk do the branchless bitonic
// "top-32 of (run U batch)": run[i] = max(run[i], b64[15-i]) then 5-stage
// half-clean. ~8.5K ILP-rich ops/thread, no divergence, no dependent scans
// (old insertion-scan version: 438 us, VALUBusy 4%, pure latency).
__global__ __launch_bounds__(64) void kmerge(const unsigned* __restrict__ cand,
                                             int* __restrict__ candIdx) {
  int row = blockIdx.x * 64 + threadIdx.x;
  if (row >= N_NODES) return;
  unsigned long long run[TOPM];
#pragma unroll
  for (int s = 0; s < TOPM; s++) run[s] = 0ull;
  const uint4* c4 = (const uint4*)(cand + (size_t)row * (NCH * 16));
  for (int ch = 0; ch < NCH; ch++) {
    unsigned b[16];
#pragma unroll
    for (int q = 0; q < 4; q++) {
      uint4 t = c4[ch * 4 + q];
      b[q * 4 + 0] = t.x; b[q * 4 + 1] = t.y;
      b[q * 4 + 2] = t.z; b[q * 4 + 3] = t.w;
    }
    unsigned base = (unsigned)(ch * CHUNK);
    unsigned long long b64[16];
#pragma unroll
    for (int s = 0; s < 16; s++) {
      unsigned k = b[s];
      unsigned gcol = base + (1023u - (k & 1023u));
      b64[s] = ((unsigned long long)(k >> 10) << 32) | (unsigned long long)(~gcol);
    }
#pragma unroll
    for (int i = 0; i < 16; i++) run[i] = max(run[i], b64[15 - i]);
#pragma unroll
    for (int j = 16; j > 0; j >>= 1)
#pragma unroll
      for (int i = 0; i < TOPM; i++)
        if ((i & j) == 0) ceu64(run[i], run[i + j]);
  }
  int4* o4 = (int4*)(candIdx + (size_t)row * TOPM);
#pragma unroll
  for (int s = 0; s < TOPM; s += 4) {
    int4 o;
    o.x = (int)(~(unsigned)(run[s + 0] & 0xFFFFFFFFull));
    o.y = (int)(~(unsigned)(run[s + 1] & 0xFFFFFFFFull));
    o.z = (int)(~(unsigned)(run[s + 2] & 0xFFFFFFFFull));
    o.w = (int)(~(unsigned)(run[s + 3] & 0xFFFFFFFFull));
    o4[s >> 2] = o;
  }
}

// ---------------- f64 exact re-rank of 32 candidates -> knn top-16 ----------------
__global__ __launch_bounds__(256) void krerank(const float* __restrict__ feats,
                                               const double* __restrict__ normD,
                                               const int* __restrict__ candIdx,
                                               int* __restrict__ knn) {
  __shared__ float rowF[D];
  __shared__ double simL[TOPM];
  __shared__ int idxL[TOPM];
  int row = blockIdx.x;
  int tid = threadIdx.x;
  if (tid < DQ)
    ((float4*)rowF)[tid] = ((const float4*)(feats + (size_t)row * D))[tid];
  int c = tid >> 3, part = tid & 7;
  int cnd = candIdx[(size_t)row * TOPM + c];
  __syncthreads();
  const float4* f4 = (const float4*)(feats + (size_t)cnd * D);
  double acc = 0.0;
#pragma unroll
  for (int g = 0; g < 4; g++) {
    float4 v = f4[part * 4 + g];
    const float* rf = &rowF[(part * 4 + g) * 4];
    acc = fma((double)v.x, (double)rf[0], acc);
    acc = fma((double)v.y, (double)rf[1], acc);
    acc = fma((double)v.z, (double)rf[2], acc);
    acc = fma((double)v.w, (double)rf[3], acc);
  }
  acc += __shfl_down(acc, 4);
  acc += __shfl_down(acc, 2);
  acc += __shfl_down(acc, 1);
  if (part == 0) {
    simL[c] = acc / (normD[row] * normD[cnd]);
    idxL[c] = cnd;
  }
  __syncthreads();
  if (tid < TOPM) {
    double s = simL[tid];
    int idx = idxL[tid];
    int rank = 0;
#pragma unroll
    for (int o = 0; o < TOPM; o++) {
      double so = simL[o];
      int io = idxL[o];
      rank += (so > s || (so == s && io < idx)) ? 1 : 0;
    }
    if (rank < TOPK) knn[(size_t)row * TOPK + rank] = idx;
  }
}

// ---------------- mult GEMM (batched, K=16, 4 branches via blockIdx.z) ----------------
__global__ __launch_bounds__(128) void kmult16x4(const float* __restrict__ feats,
    const int* __restrict__ cluster_idx, const int* __restrict__ knn,
    const float* __restrict__ wKK_c, const float* __restrict__ bKK_c,
    const float* __restrict__ wKK_n, const float* __restrict__ bKK_n,
    float* __restrict__ mult) {
  const int K = 16, NT = 128;
  __shared__ float ATl[32][132];
  __shared__ float WTl[32][K + 4];
  __shared__ int idxL[128];
  int z = blockIdx.z;
  const int* idxTab; int idxStride, idxOff;
  const float* wKK; const float* bKK;
  if (z < 3) { idxTab = cluster_idx; idxStride = NCB * 16; idxOff = z * 16; wKK = wKK_c; bKK = bKK_c; }
  else       { idxTab = knn;         idxStride = 16;       idxOff = 0;      wKK = wKK_n; bKK = bKK_n; }
  float* multBuf = mult + (size_t)z * 2560000;
  int tid = threadIdx.x;
  int i = blockIdx.y;
  int n0 = blockIdx.x * 128;
  if (tid < 128) {
    int node = n0 + tid;
    idxL[tid] = (node < N_NODES) ? idxTab[(size_t)node * idxStride + idxOff + i] : 0;
  }
  int nq = tid & 31, jq = tid >> 5;
  float acc[4][4];
#pragma unroll
  for (int m = 0; m < 4; m++)
#pragma unroll
    for (int j = 0; j < 4; j++) acc[m][j] = 0.f;
  const float4* f4 = (const float4*)feats;
  const float4* w4 = (const float4*)wKK;
  __syncthreads();
  for (int kc = 0; kc < D; kc += 32) {
    for (int q = tid; q < 1024; q += NT) {
      int node = q & 127, kg = q >> 7;
      float4 val = f4[(size_t)idxL[node] * DQ + (kc >> 2) + kg];
      int kl = kg << 2;
      ATl[kl + 0][node] = val.x; ATl[kl + 1][node] = val.y;
      ATl[kl + 2][node] = val.z; ATl[kl + 3][node] = val.w;
    }
    for (int q = tid; q < K * 8; q += NT) {
      int j = q & (K - 1), kg = q / K;
      float4 val = w4[((size_t)i * K + j) * DQ + (kc >> 2) + kg];
      int kl = kg << 2;
      WTl[kl + 0][j] = val.x; WTl[kl + 1][j] = val.y;
      WTl[kl + 2][j] = val.z; WTl[kl + 3][j] = val.w;
    }
    __syncthreads();
#pragma unroll
    for (int k = 0; k < 32; k++) {
      float4 a = *(const float4*)&ATl[k][nq << 2];
      float4 wv = *(const float4*)&WTl[k][jq << 2];
      float am[4] = {a.x, a.y, a.z, a.w};
      float wm[4] = {wv.x, wv.y, wv.z, wv.w};
#pragma unroll
      for (int m = 0; m < 4; m++)
#pragma unroll
        for (int j = 0; j < 4; j++) acc[m][j] = fmaf(am[m], wm[j], acc[m][j]);
    }
    __syncthreads();
  }
#pragma unroll
  for (int m = 0; m < 4; m++) {
    int node = n0 + (nq << 2) + m;
    if (node < N_NODES) {
      float4 o;
      o.x = acc[m][0] + bKK[i * K + (jq << 2) + 0];
      o.y = acc[m][1] + bKK[i * K + (jq << 2) + 1];
      o.z = acc[m][2] + bKK[i * K + (jq << 2) + 2];
      o.w = acc[m][3] + bKK[i * K + (jq << 2) + 3];
      ((float4*)multBuf)[((size_t)node * K + i) * (K / 4) + jq] = o;
    }
  }
}

// ---------------- mult GEMM (K=32, struct) ----------------
template <int K>
__global__ __launch_bounds__(256) void kmult(const float* __restrict__ feats,
    const int* __restrict__ idxTab, int idxStride, int idxOff,
    const float* __restrict__ wKK, const float* __restrict__ bKK,
    float* __restrict__ multBuf) {
  constexpr int NT = 8 * K;
  constexpr int JG = K / 4;
  __shared__ float ATl[32][132];
  __shared__ float WTl[32][K + 4];
  __shared__ int idxL[128];
  int tid = threadIdx.x;
  int i = blockIdx.y;
  int n0 = blockIdx.x * 128;
  if (tid < 128) {
    int node = n0 + tid;
    idxL[tid] = (node < N_NODES) ? idxTab[(size_t)node * idxStride + idxOff + i] : 0;
  }
  int nq = tid & 31, jq = tid >> 5;
  float acc[4][4];
#pragma unroll
  for (int m = 0; m < 4; m++)
#pragma unroll
    for (int j = 0; j < 4; j++) acc[m][j] = 0.f;
  const float4* f4 = (const float4*)feats;
  const float4* w4 = (const float4*)wKK;
  __syncthreads();
  for (int kc = 0; kc < D; kc += 32) {
    for (int q = tid; q < 1024; q += NT) {
      int node = q & 127, kg = q >> 7;
      float4 val = f4[(size_t)idxL[node] * DQ + (kc >> 2) + kg];
      int kl = kg << 2;
      ATl[kl + 0][node] = val.x; ATl[kl + 1][node] = val.y;
      ATl[kl + 2][node] = val.z; ATl[kl + 3][node] = val.w;
    }
    for (int q = tid; q < K * 8; q += NT) {
      int j = q & (K - 1), kg = q / K;
      float4 val = w4[((size_t)i * K + j) * DQ + (kc >> 2) + kg];
      int kl = kg << 2;
      WTl[kl + 0][j] = val.x; WTl[kl + 1][j] = val.y;
      WTl[kl + 2][j] = val.z; WTl[kl + 3][j] = val.w;
    }
    __syncthreads();
#pragma unroll
    for (int k = 0; k < 32; k++) {
      float4 a = *(const float4*)&ATl[k][nq << 2];
      float4 wv = *(const float4*)&WTl[k][jq << 2];
      float am[4] = {a.x, a.y, a.z, a.w};
      float wm[4] = {wv.x, wv.y, wv.z, wv.w};
#pragma unroll
      for (int m = 0; m < 4; m++)
#pragma unroll
        for (int j = 0; j < 4; j++) acc[m][j] = fmaf(am[m], wm[j], acc[m][j]);
    }
    __syncthreads();
  }
#pragma unroll
  for (int m = 0; m < 4; m++) {
    int node = n0 + (nq << 2) + m;
    if (node < N_NODES) {
      float4 o;
      o.x = acc[m][0] + bKK[i * K + (jq << 2) + 0];
      o.y = acc[m][1] + bKK[i * K + (jq << 2) + 1];
      o.z = acc[m][2] + bKK[i * K + (jq << 2) + 2];
      o.w = acc[m][3] + bKK[i * K + (jq << 2) + 3];
      ((float4*)multBuf)[((size_t)node * K + i) * JG + jq] = o;
    }
  }
}

// ---------------- softmax + coef + gather-combine (batched K=16) ----------------
__global__ __launch_bounds__(256) void kvconv16x4(const float* __restrict__ feats,
    const int* __restrict__ cluster_idx, const int* __restrict__ knn,
    const float* __restrict__ mult,
    const float* __restrict__ wK1_c, const float* __restrict__ bK1_c,
    const float* __restrict__ wK1_n, const float* __restrict__ bK1_n,
    float* __restrict__ hx) {
  const int K = 16;
  __shared__ float multL[8][K][K + 1];
  __shared__ float aL[8][K];
  __shared__ float coefL[8][K];
  __shared__ int idxL[8][K];
  int z = blockIdx.y;
  const int* idxTab; int idxStride, idxOff;
  const float* wK1; const float* bK1p;
  if (z < 3) { idxTab = cluster_idx; idxStride = NCB * 16; idxOff = z * 16; wK1 = wK1_c; bK1p = bK1_c; }
  else       { idxTab = knn;         idxStride = 16;       idxOff = 0;      wK1 = wK1_n; bK1p = bK1_n; }
  const float* multBuf = mult + (size_t)z * 2560000;
  int tslot = z;
  int tid = threadIdx.x;
  int n0 = blockIdx.x * 8;
  for (int q = tid; q < 8 * K; q += 256) {
    int nn = q / K, j = q & (K - 1);
    int node = n0 + nn;
    idxL[nn][j] = (node < N_NODES) ? idxTab[(size_t)node * idxStride + idxOff + j] : 0;
  }
  for (int q = tid; q < 8 * K * K; q += 256) {
    int nn = q / (K * K);
    int rem = q - nn * K * K;
    int node = n0 + nn;
    multL[nn][rem / K][rem & (K - 1)] = (node < N_NODES) ? multBuf[(size_t)node * K * K + rem] : 0.f;
  }
  __syncthreads();
  for (int q = tid; q < 8 * K; q += 256) {
    int nn = q / K, ii = q & (K - 1);
    float mx = -1e30f;
    for (int j = 0; j < K; j++) mx = fmaxf(mx, multL[nn][ii][j]);
    float s = 0.f;
    for (int j = 0; j < K; j++) {
      float e = expf(multL[nn][ii][j] - mx);
      multL[nn][ii][j] = e;
      s += e;
    }
    aL[nn][ii] = wK1[ii] / s;
  }
  __syncthreads();
  for (int q = tid; q < 8 * K; q += 256) {
    int nn = q / K, j = q & (K - 1);
    float cs = 0.f;
    for (int ii = 0; ii < K; ii++) cs = fmaf(aL[nn][ii], multL[nn][ii][j], cs);
    coefL[nn][j] = cs;
  }
  __syncthreads();
  {
    int nn = tid >> 5, dq = tid & 31;
    int node = n0 + nn;
    if (node < N_NODES) {
      float bk1 = bK1p[0];
      float4 accv = make_float4(bk1, bk1, bk1, bk1);
      const float4* f4 = (const float4*)feats;
      for (int j = 0; j < K; j++) {
        float cf = coefL[nn][j];
        float4 xv = f4[(size_t)idxL[nn][j] * DQ + dq];
        accv.x = fmaf(cf, xv.x, accv.x);
        accv.y = fmaf(cf, xv.y, accv.y);
        accv.z = fmaf(cf, xv.z, accv.z);
        accv.w = fmaf(cf, xv.w, accv.w);
      }
      ((float4*)hx)[((size_t)node * T_HE + tslot) * DQ + dq] = accv;
    }
  }
}

// ---------------- softmax + coef + gather-combine (K=32, struct) ----------------
template <int K>
__global__ __launch_bounds__(256) void kvconv2(const float* __restrict__ feats,
    const int* __restrict__ idxTab, int idxStride, int idxOff,
    const float* __restrict__ multBuf, const float* __restrict__ wK1,
    const float* __restrict__ bK1p, float* __restrict__ hx, int tslot) {
  __shared__ float multL[8][K][K + 1];
  __shared__ float aL[8][K];
  __shared__ float coefL[8][K];
  __shared__ int idxL[8][K];
  int tid = threadIdx.x;
  int n0 = blockIdx.x * 8;
  for (int q = tid; q < 8 * K; q += 256) {
    int nn = q / K, j = q & (K - 1);
    int node = n0 + nn;
    idxL[nn][j] = (node < N_NODES) ? idxTab[(size_t)node * idxStride + idxOff + j] : 0;
  }
  for (int q = tid; q < 8 * K * K; q += 256) {
    int nn = q / (K * K);
    int rem = q - nn * K * K;
    int node = n0 + nn;
    multL[nn][rem / K][rem & (K - 1)] = (node < N_NODES) ? multBuf[(size_t)node * K * K + rem] : 0.f;
  }
  __syncthreads();
  for (int q = tid; q < 8 * K; q += 256) {
    int nn = q / K, ii = q & (K - 1);
    float mx = -1e30f;
    for (int j = 0; j < K; j++) mx = fmaxf(mx, multL[nn][ii][j]);
    float s = 0.f;
    for (int j = 0; j < K; j++) {
      float e = expf(multL[nn][ii][j] - mx);
      multL[nn][ii][j] = e;
      s += e;
    }
    aL[nn][ii] = wK1[ii] / s;
  }
  __syncthreads();
  for (int q = tid; q < 8 * K; q += 256) {
    int nn = q / K, j = q & (K - 1);
    float cs = 0.f;
    for (int ii = 0; ii < K; ii++) cs = fmaf(aL[nn][ii], multL[nn][ii][j], cs);
    coefL[nn][j] = cs;
  }
  __syncthreads();
  {
    int nn = tid >> 5, dq = tid & 31;
    int node = n0 + nn;
    if (node < N_NODES) {
      float bk1 = bK1p[0];
      float4 accv = make_float4(bk1, bk1, bk1, bk1);
      const float4* f4 = (const float4*)feats;
      for (int j = 0; j < K; j++) {
        float cf = coefL[nn][j];
        float4 xv = f4[(size_t)idxL[nn][j] * DQ + dq];
        accv.x = fmaf(cf, xv.x, accv.x);
        accv.y = fmaf(cf, xv.y, accv.y);
        accv.z = fmaf(cf, xv.z, accv.z);
        accv.w = fmaf(cf, xv.w, accv.w);
      }
      ((float4*)hx)[((size_t)node * T_HE + tslot) * DQ + dq] = accv;
    }
  }
}

// ---------------- edge attention + fc ----------------
__global__ __launch_bounds__(256) void kfinal(const float* __restrict__ hx,
    const float* __restrict__ w1, const float* __restrict__ b1,
    const float* __restrict__ w2, const float* __restrict__ b2p,
    const float* __restrict__ fcw, const float* __restrict__ fcb,
    float* __restrict__ out) {
  __shared__ float xL[8][T_HE][D];
  __shared__ float hL[8][T_HE][HID_SZ];
  __shared__ float scL[8][T_HE];
  __shared__ float aggL[8][D];
  int tid = threadIdx.x;
  int n0 = blockIdx.x * 8;
  const float4* hx4 = (const float4*)hx;
  for (int q = tid; q < 8 * T_HE * DQ; q += 256) {
    int nn = q / (T_HE * DQ);
    int rem = q - nn * (T_HE * DQ);
    int t = rem / DQ;
    int dq = rem & 31;
    int node = n0 + nn;
    float4 val = make_float4(0.f, 0.f, 0.f, 0.f);
    if (node < N_NODES) val = hx4[((size_t)node * T_HE + t) * DQ + dq];
    *(float4*)&xL[nn][t][dq << 2] = val;
  }
  __syncthreads();
  for (int q = tid; q < 8 * T_HE * HID_SZ; q += 256) {
    int nn = q / (T_HE * HID_SZ);
    int rem = q - nn * (T_HE * HID_SZ);
    int t = rem / HID_SZ;
    int hh = rem & (HID_SZ - 1);
    float acc = b1[hh];
    for (int d = 0; d < D; d++) acc = fmaf(xL[nn][t][d], w1[d * HID_SZ + hh], acc);
    hL[nn][t][hh] = fmaxf(acc, 0.f);
  }
  __syncthreads();
  if (tid < 8 * T_HE) {
    int nn = tid / T_HE, t = tid % T_HE;
    float acc = b2p[0];
    for (int hh = 0; hh < HID_SZ; hh++) acc = fmaf(hL[nn][t][hh], w2[hh], acc);
    scL[nn][t] = acc;
  }
  __syncthreads();
  if (tid < 8) {
    float mx = -1e30f;
#pragma unroll
    for (int t = 0; t < T_HE; t++) mx = fmaxf(mx, scL[tid][t]);
    float e[T_HE];
    float s = 0.f;
#pragma unroll
    for (int t = 0; t < T_HE; t++) { e[t] = expf(scL[tid][t] - mx); s += e[t]; }
    float inv = 1.f / s;
#pragma unroll
    for (int t = 0; t < T_HE; t++) scL[tid][t] = e[t] * inv;
  }
  __syncthreads();
  {
    int nn = tid >> 5, dq = tid & 31;
    float4 acc = make_float4(0.f, 0.f, 0.f, 0.f);
#pragma unroll
    for (int t = 0; t < T_HE; t++) {
      float sw = scL[nn][t];
      float4 xv = *(const float4*)&xL[nn][t][dq << 2];
      acc.x = fmaf(sw, xv.x, acc.x);
      acc.y = fmaf(sw, xv.y, acc.y);
      acc.z = fmaf(sw, xv.z, acc.z);
      acc.w = fmaf(sw, xv.w, acc.w);
    }
    *(float4*)&aggL[nn][dq << 2] = acc;
  }
  __syncthreads();
  {
    int dout = tid & 127, g = tid >> 7;
    float a0 = fcb[dout], a1 = a0, a2 = a0, a3 = a0;
    for (int d = 0; d < D; d++) {
      float w = fcw[d * 128 + dout];
      a0 = fmaf(aggL[g * 4 + 0][d], w, a0);
      a1 = fmaf(aggL[g * 4 + 1][d], w, a1);
      a2 = fmaf(aggL[g * 4 + 2][d], w, a2);
      a3 = fmaf(aggL[g * 4 + 3][d], w, a3);
    }
    int nb = n0 + g * 4;
    if (nb + 0 < N_NODES) out[(size_t)(nb + 0) * 128 + dout] = fmaxf(a0, 0.f);
    if (nb + 1 < N_NODES) out[(size_t)(nb + 1) * 128 + dout] = fmaxf(a1, 0.f);
    if (nb + 2 < N_NODES) out[(size_t)(nb + 2) * 128 + dout] = fmaxf(a2, 0.f);
    if (nb + 3 < N_NODES) out[(size_t)(nb + 3) * 128 + dout] = fmaxf(a3, 0.f);
  }
}

extern "C" void kernel_launch(void* const* d_in, const int* in_sizes, int n_in,
                              void* d_out, int out_size, void* d_ws, size_t ws_size,
                              hipStream_t stream) {
  (void)in_sizes; (void)n_in; (void)out_size; (void)ws_size;
  const float* feats       = (const float*)d_in[1];
  const int*   cluster_idx = (const int*)d_in[2];
  const int*   struct_idx  = (const int*)d_in[3];
  const float* wKK_c = (const float*)d_in[5];
  const float* bKK_c = (const float*)d_in[6];
  const float* wK1_c = (const float*)d_in[7];
  const float* bK1_c = (const float*)d_in[8];
  const float* wKK_n = (const float*)d_in[9];
  const float* bKK_n = (const float*)d_in[10];
  const float* wK1_n = (const float*)d_in[11];
  const float* bK1_n = (const float*)d_in[12];
  const float* wKK_s = (const float*)d_in[13];
  const float* bKK_s = (const float*)d_in[14];
  const float* wK1_s = (const float*)d_in[15];
  const float* bK1_s = (const float*)d_in[16];
  const float* ec_w1 = (const float*)d_in[17];
  const float* ec_b1 = (const float*)d_in[18];
  const float* ec_w2 = (const float*)d_in[19];
  const float* ec_b2 = (const float*)d_in[20];
  const float* fc_w  = (const float*)d_in[21];
  const float* fc_b  = (const float*)d_in[22];
  float* out = (float*)d_out;

  // ws layout (lifetime-overlapped, total 72.32 MB — proven fits):
  //  [0, 2.56M)        xnh (bf16)     dead after ksim
  //  [2.56M, 12.8M)    cand (u32)     dead after kmerge
  //  [12.8M, 14.08M)   candIdx (int)  dead after krerank
  //  [14.08M, 14.16M)  normD (f64)    dead after krerank
  //  [0, 40.96M)       mult (f32)     written after krerank (4x2.56M floats K=16; reused for K=32)
  //  [46.08M, 46.72M)  knn (int)
  //  [46.72M, 72.32M)  hx (f32)
  char* wsb = (char*)d_ws;
  unsigned short* xnh = (unsigned short*)(wsb);
  unsigned* cand = (unsigned*)(wsb + 2560000);
  int* candIdx = (int*)(wsb + 12800000);
  double* normD = (double*)(wsb + 14080000);
  float* mult = (float*)(wsb);
  int* knnIdx = (int*)(wsb + 46080000);
  float* hx = (float*)(wsb + 46720000);

  knorm<<<N_NODES, 64, 0, stream>>>(feats, xnh, normD);
  ksim<<<dim3(79, NCH), 256, 0, stream>>>(xnh, cand);
  kmerge<<<(N_NODES + 63) / 64, 64, 0, stream>>>(cand, candIdx);
  krerank<<<N_NODES, 256, 0, stream>>>(feats, normD, candIdx, knnIdx);

  kmult16x4<<<dim3(79, 16, 4), 128, 0, stream>>>(feats, cluster_idx, knnIdx,
                                                 wKK_c, bKK_c, wKK_n, bKK_n, mult);
  kvconv16x4<<<dim3(1250, 4), 256, 0, stream>>>(feats, cluster_idx, knnIdx, mult,
                                                wK1_c, bK1_c, wK1_n, bK1_n, hx);
  kmult<32><<<dim3(79, 32), 256, 0, stream>>>(feats, struct_idx, 32, 0, wKK_s, bKK_s, mult);
  kvconv2<32><<<1250, 256, 0, stream>>>(feats, struct_idx, 32, 0, mult, wK1_s, bK1_s, hx, 4);

  kfinal<<<1250, 256, 0, stream>>>(hx, ec_w1, ec_b1, ec_w2, ec_b2, fc_w, fc_b, out);
}

// Round 5
// 521.241 us; speedup vs baseline: 6.9463x; 1.0370x over previous
//
#include <hip/hip_runtime.h>
#include <cmath>

// DHGLayer on MI355X. N=10000, D=128.
// knorm (bf16 xnh + f64 norms) -> ksim (barrier-free bf16 MFMA sim + wave-local
// packed-u32 per-chunk top-16) -> kmerge (branchless bitonic merge of 16 sorted
// runs -> top-32 candidates) -> krerank (f64 exact top-16) -> kmult16x4 +
// kvconv16x4 (4 batched K=16 branches) -> kmult<32> + kvconv2<32> (struct) ->
// kfinal.
// Vertex conv collapsed: out = sum_j coef[j]*x[j,:], coef[j] = sum_i
// wK1[i]*softmax_row_i(mult)[j].
// Candidate gen may be sloppy (bf16 + 22-bit quantized keys): f64 rerank of the
// top-32 superset restores exactness (rank-16..32 gap ~0.017 >> bf16 noise 1.4e-4).

#define N_NODES 10000
#define D 128
#define DQ 32
#define NCB 3
#define T_HE 5
#define HID_SZ 32
#define NCH 16
#define CHUNK 625      // 16 * 625 = 10000
#define TOPK 16
#define TOPM 32

typedef __attribute__((ext_vector_type(8))) short short8;
typedef __attribute__((ext_vector_type(16))) float f32x16;

// ---------------- normalize -> bf16 xnh + f64 norm ----------------
__device__ __forceinline__ unsigned bf16rne(float f) {
  unsigned u = __float_as_uint(f);
  return (u + 0x7FFFu + ((u >> 16) & 1u)) >> 16;
}

__global__ __launch_bounds__(64) void knorm(const float* __restrict__ feats,
                                            unsigned short* __restrict__ xnh,
                                            double* __restrict__ normD) {
  int n = blockIdx.x;
  int lane = threadIdx.x;
  float2 v = ((const float2*)(feats + (size_t)n * D))[lane];
  double ss = (double)v.x * (double)v.x + (double)v.y * (double)v.y;
#pragma unroll
  for (int o = 32; o > 0; o >>= 1) ss += __shfl_xor(ss, o);
  double nd = fmax(sqrt(ss), 1e-12);
  if (lane == 0) normD[n] = nd;
  float inv = (float)(1.0 / nd);
  unsigned pa = bf16rne(v.x * inv), pb = bf16rne(v.y * inv);
  ((unsigned*)(xnh + (size_t)n * D))[lane] = pa | (pb << 16);
}

// ---------------- sorting-network helpers ----------------
__device__ __forceinline__ void ceu(unsigned& a, unsigned& b) {
  unsigned lo = min(a, b), hi = max(a, b);
  a = lo; b = hi;
}
__device__ __forceinline__ void ceu64(unsigned long long& a, unsigned long long& b) {
  unsigned long long lo = min(a, b), hi = max(a, b);
  a = lo; b = hi;
}
__device__ __forceinline__ void sort16_asc(unsigned (&v)[16]) {
#pragma unroll
  for (int k = 2; k <= 16; k <<= 1) {
#pragma unroll
    for (int j = k >> 1; j > 0; j >>= 1) {
#pragma unroll
      for (int i = 0; i < 16; i++) {
        int x = i ^ j;
        if (x > i) {
          if ((i & k) == 0) ceu(v[i], v[x]);
          else ceu(v[x], v[i]);
        }
      }
    }
  }
}
// run ASC, b ASC -> run = top-16 of union, ASC (bitonic half-clean + merge)
__device__ __forceinline__ void merge16_asc(unsigned (&run)[16], const unsigned (&b)[16]) {
  unsigned m[16];
#pragma unroll
  for (int i = 0; i < 16; i++) m[i] = max(run[i], b[15 - i]);
#pragma unroll
  for (int j = 8; j > 0; j >>= 1) {
#pragma unroll
    for (int i = 0; i < 16; i++) {
      if ((i & j) == 0) ceu(m[i], m[i + j]);
    }
  }
#pragma unroll
  for (int i = 0; i < 16; i++) run[i] = m[i];
}

// ---------------- barrier-free bf16 MFMA sim + per-chunk top-16 ----------------
// grid (79 row-blocks of 128, 16 chunks of 625 cols). 4 waves; wave w owns rows
// row0+w*32..+31 x ALL 128 cols of each tile (ni=4 MFMA col-blocks). A-frags
// persistent in regs; B frags loaded straight from L2-resident xnh (16B/lane,
// no LDS staging). Keys written to a wave-PRIVATE LDS buffer (stride 35 ->
// 3r mod 32, conflict-free) and scanned by the same wave: same-wave DS ops are
// in-order, so the entire kernel has ZERO __syncthreads. Final lane-pair merge
// via shfl_xor(1). LDS 17.5 KB, ~160 VGPR -> 12 waves/CU (vs old 67.5 KB,
// 8 waves/CU, ~30 barriers: 145 us, VALUBusy 38%, 4.85M bank-conflict cycles).
__global__ __launch_bounds__(256, 3) void ksim(const unsigned short* __restrict__ xnh,
                                               unsigned* __restrict__ cand) {
  __shared__ unsigned kb[4][32 * 35];   // per-wave private, 17.5 KB total
  int tid = threadIdx.x;
  int w = tid >> 6, lane = tid & 63, l31 = lane & 31, lh = lane >> 5;
  int row0 = blockIdx.x * 128 + w * 32;
  int chunk = blockIdx.y;
  int cbase = chunk * CHUNK;

  // persistent A fragments: afr[ks] = xnh[row0+l31][ks*16 + lh*8 .. +8]
  short8 afr[8];
  {
    int ar = min(row0 + l31, N_NODES - 1);
    const short8* ap = (const short8*)(xnh + (size_t)ar * D);
#pragma unroll
    for (int ks = 0; ks < 8; ks++) afr[ks] = ap[ks * 2 + lh];
  }

  unsigned run[16];
#pragma unroll
  for (int s = 0; s < 16; s++) run[s] = 0u;
  unsigned* kbw = kb[w];
  int srow = lane >> 1, soff = (lane & 1) * 16;

  for (int ti = 0; ti < 5; ti++) {
    int tb = cbase + ti * 128;
    f32x16 acc[4];
#pragma unroll
    for (int ni = 0; ni < 4; ni++)
#pragma unroll
      for (int r = 0; r < 16; r++) acc[ni][r] = 0.f;
#pragma unroll
    for (int ks = 0; ks < 8; ks++) {
#pragma unroll
      for (int ni = 0; ni < 4; ni++) {
        int col = min(tb + ni * 32 + l31, N_NODES - 1);
        short8 bf = *(const short8*)(xnh + (size_t)col * D + ks * 16 + lh * 8);
        acc[ni] = __builtin_amdgcn_mfma_f32_32x32x16_bf16(afr[ks], bf, acc[ni], 0, 0, 0);
      }
    }
    // 4 col-subs of 32: write packed keys -> wave-local scan (no barriers)
#pragma unroll
    for (int ni = 0; ni < 4; ni++) {
      int cb2 = ti * 128 + ni * 32;
#pragma unroll
      for (int reg = 0; reg < 16; reg++) {
        int r = (reg & 3) + 8 * (reg >> 2) + 4 * lh;   // C/D row within 32
        int cic = cb2 + l31;
        unsigned bb = __float_as_uint(acc[ni][reg]);
        unsigned mu = (bb & 0x80000000u) ? ~bb : (bb | 0x80000000u);
        unsigned key = (cic < CHUNK) ? ((mu & 0xFFFFFC00u) | (unsigned)(1023 - cic)) : 0u;
        kbw[r * 35 + l31] = key;
      }
      unsigned bt[16];
      const unsigned* rp = &kbw[srow * 35 + soff];
#pragma unroll
      for (int q = 0; q < 4; q++) {
        uint4 t4 = *(const uint4*)(rp + q * 4);
        bt[q * 4 + 0] = t4.x; bt[q * 4 + 1] = t4.y;
        bt[q * 4 + 2] = t4.z; bt[q * 4 + 3] = t4.w;
      }
      sort16_asc(bt);
      merge16_asc(run, bt);
    }
  }
  // lane-pair merge (rows are 2 lanes wide): exchange sorted runs via shuffle
  {
    unsigned other[16];
#pragma unroll
    for (int s = 0; s < 16; s++) other[s] = (unsigned)__shfl_xor((int)run[s], 1);
    merge16_asc(run, other);
  }
  int grow = row0 + srow;
  if ((lane & 1) == 0 && grow < N_NODES) {
    unsigned* o = cand + ((size_t)grow * NCH + chunk) * 16;
#pragma unroll
    for (int i = 0; i < 16; i += 4)
      *(uint4*)(o + i) = make_uint4(run[i], run[i + 1], run[i + 2], run[i + 3]);
  }
}

// ---------------- merge chunk keys -> top-32 candidate cols ----------------
// One thread per row. Inputs are 16 sorted-ASC runs of 16 u32 keys. Maintain a
// sorted-ASC run[32] of u64 global keys; per chunk do the branchless bitonic
// "top-32 of (run U batch)": run[i] = max(run[i], b64[15-i]) then 5-stage
// half-clean. ~8.5K ILP-rich ops/thread, no divergence, no dependent scans
// (old insertion-scan version: 438 us, VALUBusy 4%, pure latency).
__global__ __launch_bounds__(64) void kmerge(const unsigned* __restrict__ cand,
                                             int* __restrict__ candIdx) {
  int row = blockIdx.x * 64 + threadIdx.x;
  if (row >= N_NODES) return;
  unsigned long long run[TOPM];
#pragma unroll
  for (int s = 0; s < TOPM; s++) run[s] = 0ull;
  const uint4* c4 = (const uint4*)(cand + (size_t)row * (NCH * 16));
  for (int ch = 0; ch < NCH; ch++) {
    unsigned b[16];
#pragma unroll
    for (int q = 0; q < 4; q++) {
      uint4 t = c4[ch * 4 + q];
      b[q * 4 + 0] = t.x; b[q * 4 + 1] = t.y;
      b[q * 4 + 2] = t.z; b[q * 4 + 3] = t.w;
    }
    unsigned base = (unsigned)(ch * CHUNK);
    unsigned long long b64[16];
#pragma unroll
    for (int s = 0; s < 16; s++) {
      unsigned k = b[s];
      unsigned gcol = base + (1023u - (k & 1023u));
      b64[s] = ((unsigned long long)(k >> 10) << 32) | (unsigned long long)(~gcol);
    }
#pragma unroll
    for (int i = 0; i < 16; i++) run[i] = max(run[i], b64[15 - i]);
#pragma unroll
    for (int j = 16; j > 0; j >>= 1)
#pragma unroll
      for (int i = 0; i < TOPM; i++)
        if ((i & j) == 0) ceu64(run[i], run[i + j]);
  }
  int4* o4 = (int4*)(candIdx + (size_t)row * TOPM);
#pragma unroll
  for (int s = 0; s < TOPM; s += 4) {
    int4 o;
    o.x = (int)(~(unsigned)(run[s + 0] & 0xFFFFFFFFull));
    o.y = (int)(~(unsigned)(run[s + 1] & 0xFFFFFFFFull));
    o.z = (int)(~(unsigned)(run[s + 2] & 0xFFFFFFFFull));
    o.w = (int)(~(unsigned)(run[s + 3] & 0xFFFFFFFFull));
    o4[s >> 2] = o;
  }
}

// ---------------- f64 exact re-rank of 32 candidates -> knn top-16 ----------------
__global__ __launch_bounds__(256) void krerank(const float* __restrict__ feats,
                                               const double* __restrict__ normD,
                                               const int* __restrict__ candIdx,
                                               int* __restrict__ knn) {
  __shared__ float rowF[D];
  __shared__ double simL[TOPM];
  __shared__ int idxL[TOPM];
  int row = blockIdx.x;
  int tid = threadIdx.x;
  if (tid < DQ)
    ((float4*)rowF)[tid] = ((const float4*)(feats + (size_t)row * D))[tid];
  int c = tid >> 3, part = tid & 7;
  int cnd = candIdx[(size_t)row * TOPM + c];
  __syncthreads();
  const float4* f4 = (const float4*)(feats + (size_t)cnd * D);
  double acc = 0.0;
#pragma unroll
  for (int g = 0; g < 4; g++) {
    float4 v = f4[part * 4 + g];
    const float* rf = &rowF[(part * 4 + g) * 4];
    acc = fma((double)v.x, (double)rf[0], acc);
    acc = fma((double)v.y, (double)rf[1], acc);
    acc = fma((double)v.z, (double)rf[2], acc);
    acc = fma((double)v.w, (double)rf[3], acc);
  }
  acc += __shfl_down(acc, 4);
  acc += __shfl_down(acc, 2);
  acc += __shfl_down(acc, 1);
  if (part == 0) {
    simL[c] = acc / (normD[row] * normD[cnd]);
    idxL[c] = cnd;
  }
  __syncthreads();
  if (tid < TOPM) {
    double s = simL[tid];
    int idx = idxL[tid];
    int rank = 0;
#pragma unroll
    for (int o = 0; o < TOPM; o++) {
      double so = simL[o];
      int io = idxL[o];
      rank += (so > s || (so == s && io < idx)) ? 1 : 0;
    }
    if (rank < TOPK) knn[(size_t)row * TOPK + rank] = idx;
  }
}

// ---------------- mult GEMM (batched, K=16, 4 branches via blockIdx.z) ----------------
__global__ __launch_bounds__(128) void kmult16x4(const float* __restrict__ feats,
    const int* __restrict__ cluster_idx, const int* __restrict__ knn,
    const float* __restrict__ wKK_c, const float* __restrict__ bKK_c,
    const float* __restrict__ wKK_n, const float* __restrict__ bKK_n,
    float* __restrict__ mult) {
  const int K = 16, NT = 128;
  __shared__ float ATl[32][132];
  __shared__ float WTl[32][K + 4];
  __shared__ int idxL[128];
  int z = blockIdx.z;
  const int* idxTab; int idxStride, idxOff;
  const float* wKK; const float* bKK;
  if (z < 3) { idxTab = cluster_idx; idxStride = NCB * 16; idxOff = z * 16; wKK = wKK_c; bKK = bKK_c; }
  else       { idxTab = knn;         idxStride = 16;       idxOff = 0;      wKK = wKK_n; bKK = bKK_n; }
  float* multBuf = mult + (size_t)z * 2560000;
  int tid = threadIdx.x;
  int i = blockIdx.y;
  int n0 = blockIdx.x * 128;
  if (tid < 128) {
    int node = n0 + tid;
    idxL[tid] = (node < N_NODES) ? idxTab[(size_t)node * idxStride + idxOff + i] : 0;
  }
  int nq = tid & 31, jq = tid >> 5;
  float acc[4][4];
#pragma unroll
  for (int m = 0; m < 4; m++)
#pragma unroll
    for (int j = 0; j < 4; j++) acc[m][j] = 0.f;
  const float4* f4 = (const float4*)feats;
  const float4* w4 = (const float4*)wKK;
  __syncthreads();
  for (int kc = 0; kc < D; kc += 32) {
    for (int q = tid; q < 1024; q += NT) {
      int node = q & 127, kg = q >> 7;
      float4 val = f4[(size_t)idxL[node] * DQ + (kc >> 2) + kg];
      int kl = kg << 2;
      ATl[kl + 0][node] = val.x; ATl[kl + 1][node] = val.y;
      ATl[kl + 2][node] = val.z; ATl[kl + 3][node] = val.w;
    }
    for (int q = tid; q < K * 8; q += NT) {
      int j = q & (K - 1), kg = q / K;
      float4 val = w4[((size_t)i * K + j) * DQ + (kc >> 2) + kg];
      int kl = kg << 2;
      WTl[kl + 0][j] = val.x; WTl[kl + 1][j] = val.y;
      WTl[kl + 2][j] = val.z; WTl[kl + 3][j] = val.w;
    }
    __syncthreads();
#pragma unroll
    for (int k = 0; k < 32; k++) {
      float4 a = *(const float4*)&ATl[k][nq << 2];
      float4 wv = *(const float4*)&WTl[k][jq << 2];
      float am[4] = {a.x, a.y, a.z, a.w};
      float wm[4] = {wv.x, wv.y, wv.z, wv.w};
#pragma unroll
      for (int m = 0; m < 4; m++)
#pragma unroll
        for (int j = 0; j < 4; j++) acc[m][j] = fmaf(am[m], wm[j], acc[m][j]);
    }
    __syncthreads();
  }
#pragma unroll
  for (int m = 0; m < 4; m++) {
    int node = n0 + (nq << 2) + m;
    if (node < N_NODES) {
      float4 o;
      o.x = acc[m][0] + bKK[i * K + (jq << 2) + 0];
      o.y = acc[m][1] + bKK[i * K + (jq << 2) + 1];
      o.z = acc[m][2] + bKK[i * K + (jq << 2) + 2];
      o.w = acc[m][3] + bKK[i * K + (jq << 2) + 3];
      ((float4*)multBuf)[((size_t)node * K + i) * (K / 4) + jq] = o;
    }
  }
}

// ---------------- mult GEMM (K=32, struct) ----------------
template <int K>
__global__ __launch_bounds__(256) void kmult(const float* __restrict__ feats,
    const int* __restrict__ idxTab, int idxStride, int idxOff,
    const float* __restrict__ wKK, const float* __restrict__ bKK,
    float* __restrict__ multBuf) {
  constexpr int NT = 8 * K;
  constexpr int JG = K / 4;
  __shared__ float ATl[32][132];
  __shared__ float WTl[32][K + 4];
  __shared__ int idxL[128];
  int tid = threadIdx.x;
  int i = blockIdx.y;
  int n0 = blockIdx.x * 128;
  if (tid < 128) {
    int node = n0 + tid;
    idxL[tid] = (node < N_NODES) ? idxTab[(size_t)node * idxStride + idxOff + i] : 0;
  }
  int nq = tid & 31, jq = tid >> 5;
  float acc[4][4];
#pragma unroll
  for (int m = 0; m < 4; m++)
#pragma unroll
    for (int j = 0; j < 4; j++) acc[m][j] = 0.f;
  const float4* f4 = (const float4*)feats;
  const float4* w4 = (const float4*)wKK;
  __syncthreads();
  for (int kc = 0; kc < D; kc += 32) {
    for (int q = tid; q < 1024; q += NT) {
      int node = q & 127, kg = q >> 7;
      float4 val = f4[(size_t)idxL[node] * DQ + (kc >> 2) + kg];
      int kl = kg << 2;
      ATl[kl + 0][node] = val.x; ATl[kl + 1][node] = val.y;
      ATl[kl + 2][node] = val.z; ATl[kl + 3][node] = val.w;
    }
    for (int q = tid; q < K * 8; q += NT) {
      int j = q & (K - 1), kg = q / K;
      float4 val = w4[((size_t)i * K + j) * DQ + (kc >> 2) + kg];
      int kl = kg << 2;
      WTl[kl + 0][j] = val.x; WTl[kl + 1][j] = val.y;
      WTl[kl + 2][j] = val.z; WTl[kl + 3][j] = val.w;
    }
    __syncthreads();
#pragma unroll
    for (int k = 0; k < 32; k++) {
      float4 a = *(const float4*)&ATl[k][nq << 2];
      float4 wv = *(const float4*)&WTl[k][jq << 2];
      float am[4] = {a.x, a.y, a.z, a.w};
      float wm[4] = {wv.x, wv.y, wv.z, wv.w};
#pragma unroll
      for (int m = 0; m < 4; m++)
#pragma unroll
        for (int j = 0; j < 4; j++) acc[m][j] = fmaf(am[m], wm[j], acc[m][j]);
    }
    __syncthreads();
  }
#pragma unroll
  for (int m = 0; m < 4; m++) {
    int node = n0 + (nq << 2) + m;
    if (node < N_NODES) {
      float4 o;
      o.x = acc[m][0] + bKK[i * K + (jq << 2) + 0];
      o.y = acc[m][1] + bKK[i * K + (jq << 2) + 1];
      o.z = acc[m][2] + bKK[i * K + (jq << 2) + 2];
      o.w = acc[m][3] + bKK[i * K + (jq << 2) + 3];
      ((float4*)multBuf)[((size_t)node * K + i) * JG + jq] = o;
    }
  }
}

// ---------------- softmax + coef + gather-combine (batched K=16) ----------------
__global__ __launch_bounds__(256) void kvconv16x4(const float* __restrict__ feats,
    const int* __restrict__ cluster_idx, const int* __restrict__ knn,
    const float* __restrict__ mult,
    const float* __restrict__ wK1_c, const float* __restrict__ bK1_c,
    const float* __restrict__ wK1_n, const float* __restrict__ bK1_n,
    float* __restrict__ hx) {
  const int K = 16;
  __shared__ float multL[8][K][K + 1];
  __shared__ float aL[8][K];
  __shared__ float coefL[8][K];
  __shared__ int idxL[8][K];
  int z = blockIdx.y;
  const int* idxTab; int idxStride, idxOff;
  const float* wK1; const float* bK1p;
  if (z < 3) { idxTab = cluster_idx; idxStride = NCB * 16; idxOff = z * 16; wK1 = wK1_c; bK1p = bK1_c; }
  else       { idxTab = knn;         idxStride = 16;       idxOff = 0;      wK1 = wK1_n; bK1p = bK1_n; }
  const float* multBuf = mult + (size_t)z * 2560000;
  int tslot = z;
  int tid = threadIdx.x;
  int n0 = blockIdx.x * 8;
  for (int q = tid; q < 8 * K; q += 256) {
    int nn = q / K, j = q & (K - 1);
    int node = n0 + nn;
    idxL[nn][j] = (node < N_NODES) ? idxTab[(size_t)node * idxStride + idxOff + j] : 0;
  }
  for (int q = tid; q < 8 * K * K; q += 256) {
    int nn = q / (K * K);
    int rem = q - nn * K * K;
    int node = n0 + nn;
    multL[nn][rem / K][rem & (K - 1)] = (node < N_NODES) ? multBuf[(size_t)node * K * K + rem] : 0.f;
  }
  __syncthreads();
  for (int q = tid; q < 8 * K; q += 256) {
    int nn = q / K, ii = q & (K - 1);
    float mx = -1e30f;
    for (int j = 0; j < K; j++) mx = fmaxf(mx, multL[nn][ii][j]);
    float s = 0.f;
    for (int j = 0; j < K; j++) {
      float e = expf(multL[nn][ii][j] - mx);
      multL[nn][ii][j] = e;
      s += e;
    }
    aL[nn][ii] = wK1[ii] / s;
  }
  __syncthreads();
  for (int q = tid; q < 8 * K; q += 256) {
    int nn = q / K, j = q & (K - 1);
    float cs = 0.f;
    for (int ii = 0; ii < K; ii++) cs = fmaf(aL[nn][ii], multL[nn][ii][j], cs);
    coefL[nn][j] = cs;
  }
  __syncthreads();
  {
    int nn = tid >> 5, dq = tid & 31;
    int node = n0 + nn;
    if (node < N_NODES) {
      float bk1 = bK1p[0];
      float4 accv = make_float4(bk1, bk1, bk1, bk1);
      const float4* f4 = (const float4*)feats;
      for (int j = 0; j < K; j++) {
        float cf = coefL[nn][j];
        float4 xv = f4[(size_t)idxL[nn][j] * DQ + dq];
        accv.x = fmaf(cf, xv.x, accv.x);
        accv.y = fmaf(cf, xv.y, accv.y);
        accv.z = fmaf(cf, xv.z, accv.z);
        accv.w = fmaf(cf, xv.w, accv.w);
      }
      ((float4*)hx)[((size_t)node * T_HE + tslot) * DQ + dq] = accv;
    }
  }
}

// ---------------- softmax + coef + gather-combine (K=32, struct) ----------------
template <int K>
__global__ __launch_bounds__(256) void kvconv2(const float* __restrict__ feats,
    const int* __restrict__ idxTab, int idxStride, int idxOff,
    const float* __restrict__ multBuf, const float* __restrict__ wK1,
    const float* __restrict__ bK1p, float* __restrict__ hx, int tslot) {
  __shared__ float multL[8][K][K + 1];
  __shared__ float aL[8][K];
  __shared__ float coefL[8][K];
  __shared__ int idxL[8][K];
  int tid = threadIdx.x;
  int n0 = blockIdx.x * 8;
  for (int q = tid; q < 8 * K; q += 256) {
    int nn = q / K, j = q & (K - 1);
    int node = n0 + nn;
    idxL[nn][j] = (node < N_NODES) ? idxTab[(size_t)node * idxStride + idxOff + j] : 0;
  }
  for (int q = tid; q < 8 * K * K; q += 256) {
    int nn = q / (K * K);
    int rem = q - nn * K * K;
    int node = n0 + nn;
    multL[nn][rem / K][rem & (K - 1)] = (node < N_NODES) ? multBuf[(size_t)node * K * K + rem] : 0.f;
  }
  __syncthreads();
  for (int q = tid; q < 8 * K; q += 256) {
    int nn = q / K, ii = q & (K - 1);
    float mx = -1e30f;
    for (int j = 0; j < K; j++) mx = fmaxf(mx, multL[nn][ii][j]);
    float s = 0.f;
    for (int j = 0; j < K; j++) {
      float e = expf(multL[nn][ii][j] - mx);
      multL[nn][ii][j] = e;
      s += e;
    }
    aL[nn][ii] = wK1[ii] / s;
  }
  __syncthreads();
  for (int q = tid; q < 8 * K; q += 256) {
    int nn = q / K, j = q & (K - 1);
    float cs = 0.f;
    for (int ii = 0; ii < K; ii++) cs = fmaf(aL[nn][ii], multL[nn][ii][j], cs);
    coefL[nn][j] = cs;
  }
  __syncthreads();
  {
    int nn = tid >> 5, dq = tid & 31;
    int node = n0 + nn;
    if (node < N_NODES) {
      float bk1 = bK1p[0];
      float4 accv = make_float4(bk1, bk1, bk1, bk1);
      const float4* f4 = (const float4*)feats;
      for (int j = 0; j < K; j++) {
        float cf = coefL[nn][j];
        float4 xv = f4[(size_t)idxL[nn][j] * DQ + dq];
        accv.x = fmaf(cf, xv.x, accv.x);
        accv.y = fmaf(cf, xv.y, accv.y);
        accv.z = fmaf(cf, xv.z, accv.z);
        accv.w = fmaf(cf, xv.w, accv.w);
      }
      ((float4*)hx)[((size_t)node * T_HE + tslot) * DQ + dq] = accv;
    }
  }
}

// ---------------- edge attention + fc ----------------
__global__ __launch_bounds__(256) void kfinal(const float* __restrict__ hx,
    const float* __restrict__ w1, const float* __restrict__ b1,
    const float* __restrict__ w2, const float* __restrict__ b2p,
    const float* __restrict__ fcw, const float* __restrict__ fcb,
    float* __restrict__ out) {
  __shared__ float xL[8][T_HE][D];
  __shared__ float hL[8][T_HE][HID_SZ];
  __shared__ float scL[8][T_HE];
  __shared__ float aggL[8][D];
  int tid = threadIdx.x;
  int n0 = blockIdx.x * 8;
  const float4* hx4 = (const float4*)hx;
  for (int q = tid; q < 8 * T_HE * DQ; q += 256) {
    int nn = q / (T_HE * DQ);
    int rem = q - nn * (T_HE * DQ);
    int t = rem / DQ;
    int dq = rem & 31;
    int node = n0 + nn;
    float4 val = make_float4(0.f, 0.f, 0.f, 0.f);
    if (node < N_NODES) val = hx4[((size_t)node * T_HE + t) * DQ + dq];
    *(float4*)&xL[nn][t][dq << 2] = val;
  }
  __syncthreads();
  for (int q = tid; q < 8 * T_HE * HID_SZ; q += 256) {
    int nn = q / (T_HE * HID_SZ);
    int rem = q - nn * (T_HE * HID_SZ);
    int t = rem / HID_SZ;
    int hh = rem & (HID_SZ - 1);
    float acc = b1[hh];
    for (int d = 0; d < D; d++) acc = fmaf(xL[nn][t][d], w1[d * HID_SZ + hh], acc);
    hL[nn][t][hh] = fmaxf(acc, 0.f);
  }
  __syncthreads();
  if (tid < 8 * T_HE) {
    int nn = tid / T_HE, t = tid % T_HE;
    float acc = b2p[0];
    for (int hh = 0; hh < HID_SZ; hh++) acc = fmaf(hL[nn][t][hh], w2[hh], acc);
    scL[nn][t] = acc;
  }
  __syncthreads();
  if (tid < 8) {
    float mx = -1e30f;
#pragma unroll
    for (int t = 0; t < T_HE; t++) mx = fmaxf(mx, scL[tid][t]);
    float e[T_HE];
    float s = 0.f;
#pragma unroll
    for (int t = 0; t < T_HE; t++) { e[t] = expf(scL[tid][t] - mx); s += e[t]; }
    float inv = 1.f / s;
#pragma unroll
    for (int t = 0; t < T_HE; t++) scL[tid][t] = e[t] * inv;
  }
  __syncthreads();
  {
    int nn = tid >> 5, dq = tid & 31;
    float4 acc = make_float4(0.f, 0.f, 0.f, 0.f);
#pragma unroll
    for (int t = 0; t < T_HE; t++) {
      float sw = scL[nn][t];
      float4 xv = *(const float4*)&xL[nn][t][dq << 2];
      acc.x = fmaf(sw, xv.x, acc.x);
      acc.y = fmaf(sw, xv.y, acc.y);
      acc.z = fmaf(sw, xv.z, acc.z);
      acc.w = fmaf(sw, xv.w, acc.w);
    }
    *(float4*)&aggL[nn][dq << 2] = acc;
  }
  __syncthreads();
  {
    int dout = tid & 127, g = tid >> 7;
    float a0 = fcb[dout], a1 = a0, a2 = a0, a3 = a0;
    for (int d = 0; d < D; d++) {
      float w = fcw[d * 128 + dout];
      a0 = fmaf(aggL[g * 4 + 0][d], w, a0);
      a1 = fmaf(aggL[g * 4 + 1][d], w, a1);
      a2 = fmaf(aggL[g * 4 + 2][d], w, a2);
      a3 = fmaf(aggL[g * 4 + 3][d], w, a3);
    }
    int nb = n0 + g * 4;
    if (nb + 0 < N_NODES) out[(size_t)(nb + 0) * 128 + dout] = fmaxf(a0, 0.f);
    if (nb + 1 < N_NODES) out[(size_t)(nb + 1) * 128 + dout] = fmaxf(a1, 0.f);
    if (nb + 2 < N_NODES) out[(size_t)(nb + 2) * 128 + dout] = fmaxf(a2, 0.f);
    if (nb + 3 < N_NODES) out[(size_t)(nb + 3) * 128 + dout] = fmaxf(a3, 0.f);
  }
}

extern "C" void kernel_launch(void* const* d_in, const int* in_sizes, int n_in,
                              void* d_out, int out_size, void* d_ws, size_t ws_size,
                              hipStream_t stream) {
  (void)in_sizes; (void)n_in; (void)out_size; (void)ws_size;
  const float* feats       = (const float*)d_in[1];
  const int*   cluster_idx = (const int*)d_in[2];
  const int*   struct_idx  = (const int*)d_in[3];
  const float* wKK_c = (const float*)d_in[5];
  const float* bKK_c = (const float*)d_in[6];
  const float* wK1_c = (const float*)d_in[7];
  const float* bK1_c = (const float*)d_in[8];
  const float* wKK_n = (const float*)d_in[9];
  const float* bKK_n = (const float*)d_in[10];
  const float* wK1_n = (const float*)d_in[11];
  const float* bK1_n = (const float*)d_in[12];
  const float* wKK_s = (const float*)d_in[13];
  const float* bKK_s = (const float*)d_in[14];
  const float* wK1_s = (const float*)d_in[15];
  const float* bK1_s = (const float*)d_in[16];
  const float* ec_w1 = (const float*)d_in[17];
  const float* ec_b1 = (const float*)d_in[18];
  const float* ec_w2 = (const float*)d_in[19];
  const float* ec_b2 = (const float*)d_in[20];
  const float* fc_w  = (const float*)d_in[21];
  const float* fc_b  = (const float*)d_in[22];
  float* out = (float*)d_out;

  // ws layout (lifetime-overlapped, total 72.32 MB — proven fits):
  //  [0, 2.56M)        xnh (bf16)     dead after ksim
  //  [2.56M, 12.8M)    cand (u32)     dead after kmerge
  //  [12.8M, 14.08M)   candIdx (int)  dead after krerank
  //  [14.08M, 14.16M)  normD (f64)    dead after krerank
  //  [0, 40.96M)       mult (f32)     written after krerank (4x2.56M floats K=16; reused for K=32)
  //  [46.08M, 46.72M)  knn (int)
  //  [46.72M, 72.32M)  hx (f32)
  char* wsb = (char*)d_ws;
  unsigned short* xnh = (unsigned short*)(wsb);
  unsigned* cand = (unsigned*)(wsb + 2560000);
  int* candIdx = (int*)(wsb + 12800000);
  double* normD = (double*)(wsb + 14080000);
  float* mult = (float*)(wsb);
  int* knnIdx = (int*)(wsb + 46080000);
  float* hx = (float*)(wsb + 46720000);

  knorm<<<N_NODES, 64, 0, stream>>>(feats, xnh, normD);
  ksim<<<dim3(79, NCH), 256, 0, stream>>>(xnh, cand);
  kmerge<<<(N_NODES + 63) / 64, 64, 0, stream>>>(cand, candIdx);
  krerank<<<N_NODES, 256, 0, stream>>>(feats, normD, candIdx, knnIdx);

  kmult16x4<<<dim3(79, 16, 4), 128, 0, stream>>>(feats, cluster_idx, knnIdx,
                                                 wKK_c, bKK_c, wKK_n, bKK_n, mult);
  kvconv16x4<<<dim3(1250, 4), 256, 0, stream>>>(feats, cluster_idx, knnIdx, mult,
                                                wK1_c, bK1_c, wK1_n, bK1_n, hx);
  kmult<32><<<dim3(79, 32), 256, 0, stream>>>(feats, struct_idx, 32, 0, wKK_s, bKK_s, mult);
  kvconv2<32><<<1250, 256, 0, stream>>>(feats, struct_idx, 32, 0, mult, wK1_s, bK1_s, hx, 4);

  kfinal<<<1250, 256, 0, stream>>>(hx, ec_w1, ec_b1, ec_w2, ec_b2, fc_w, fc_b, out);
}

// Round 6
// 474.576 us; speedup vs baseline: 7.6294x; 1.0983x over previous
//
#include <hip/hip_runtime.h>
#include <cmath>

// DHGLayer on MI355X. N=10000, D=128.
// knorm (bf16 xnh + f64 norms) -> ksim (bf16 MFMA sim: coalesced LDS B-staging
// + wave-local packed-u32 per-chunk top-16 scan, 2 barriers/tile) -> kmerge
// (branchless bitonic merge -> top-32 candidates) -> krerank (f64 exact top-16)
// -> kmult16x4 + kvconv16x4 (4 batched K=16 branches) -> kmult<32> +
// kvconv2<32> (struct) -> kfinal.
// Vertex conv collapsed: out = sum_j coef[j]*x[j,:], coef[j] = sum_i
// wK1[i]*softmax_row_i(mult)[j].
// Candidate gen may be sloppy (bf16 + 22-bit quantized keys): f64 rerank of the
// top-32 superset restores exactness (rank-16..32 gap ~0.017 >> bf16 noise 1.4e-4).
// R5 lesson: direct-from-L2 B-operand gathers (lane-per-row, 256B stride) cost
// 4KB of lines per 1KB used -> 145us floor regardless of barriers/conflicts.
// Stage B through LDS with full-line coalesced loads; same fix for kmult A/W.

#define N_NODES 10000
#define D 128
#define DQ 32
#define NCB 3
#define T_HE 5
#define HID_SZ 32
#define NCH 16
#define CHUNK 625      // 16 * 625 = 10000
#define TOPK 16
#define TOPM 32

typedef __attribute__((ext_vector_type(8))) short short8;
typedef __attribute__((ext_vector_type(16))) float f32x16;

// ---------------- normalize -> bf16 xnh + f64 norm ----------------
__device__ __forceinline__ unsigned bf16rne(float f) {
  unsigned u = __float_as_uint(f);
  return (u + 0x7FFFu + ((u >> 16) & 1u)) >> 16;
}

__global__ __launch_bounds__(64) void knorm(const float* __restrict__ feats,
                                            unsigned short* __restrict__ xnh,
                                            double* __restrict__ normD) {
  int n = blockIdx.x;
  int lane = threadIdx.x;
  float2 v = ((const float2*)(feats + (size_t)n * D))[lane];
  double ss = (double)v.x * (double)v.x + (double)v.y * (double)v.y;
#pragma unroll
  for (int o = 32; o > 0; o >>= 1) ss += __shfl_xor(ss, o);
  double nd = fmax(sqrt(ss), 1e-12);
  if (lane == 0) normD[n] = nd;
  float inv = (float)(1.0 / nd);
  unsigned pa = bf16rne(v.x * inv), pb = bf16rne(v.y * inv);
  ((unsigned*)(xnh + (size_t)n * D))[lane] = pa | (pb << 16);
}

// ---------------- sorting-network helpers ----------------
__device__ __forceinline__ void ceu(unsigned& a, unsigned& b) {
  unsigned lo = min(a, b), hi = max(a, b);
  a = lo; b = hi;
}
__device__ __forceinline__ void ceu64(unsigned long long& a, unsigned long long& b) {
  unsigned long long lo = min(a, b), hi = max(a, b);
  a = lo; b = hi;
}
__device__ __forceinline__ void sort16_asc(unsigned (&v)[16]) {
#pragma unroll
  for (int k = 2; k <= 16; k <<= 1) {
#pragma unroll
    for (int j = k >> 1; j > 0; j >>= 1) {
#pragma unroll
      for (int i = 0; i < 16; i++) {
        int x = i ^ j;
        if (x > i) {
          if ((i & k) == 0) ceu(v[i], v[x]);
          else ceu(v[x], v[i]);
        }
      }
    }
  }
}
// run ASC, b ASC -> run = top-16 of union, ASC (bitonic half-clean + merge)
__device__ __forceinline__ void merge16_asc(unsigned (&run)[16], const unsigned (&b)[16]) {
  unsigned m[16];
#pragma unroll
  for (int i = 0; i < 16; i++) m[i] = max(run[i], b[15 - i]);
#pragma unroll
  for (int j = 8; j > 0; j >>= 1) {
#pragma unroll
    for (int i = 0; i < 16; i++) {
      if ((i & j) == 0) ceu(m[i], m[i + j]);
    }
  }
#pragma unroll
  for (int i = 0; i < 16; i++) run[i] = m[i];
}

// ---------------- bf16 MFMA sim + per-chunk top-16 ----------------
// grid (79 row-blocks of 128, 16 chunks of 625 cols). 4 waves; wave w owns rows
// row0+w*32..+31 x ALL 128 cols of each tile. A-frags persistent in regs
// (one-time gather). B staged cooperatively into LDS k-major with FULL-LINE
// coalesced global reads (64 lanes = 32 rows x 2 contiguous halves), then read
// as conflict-free b128 fragments. Keys go to a wave-PRIVATE LDS buffer
// (stride 35) scanned by the same wave (in-order DS ops, no barrier); only 2
// barriers per tile guard the shared B buffer. Final lane-pair merge via
// shfl_xor(1). LDS 49.5 KB -> 3 blocks/CU (12 waves).
__global__ __launch_bounds__(256, 3) void ksim(const unsigned short* __restrict__ xnh,
                                               unsigned* __restrict__ cand) {
  __shared__ short Bb[16 * 128 * 8];    // [kp][ci][8 bf16] = 32 KB
  __shared__ unsigned kb[4][32 * 35];   // per-wave private, 17.5 KB
  int tid = threadIdx.x;
  int w = tid >> 6, lane = tid & 63, l31 = lane & 31, lh = lane >> 5;
  int row0 = blockIdx.x * 128 + w * 32;
  int chunk = blockIdx.y;
  int cbase = chunk * CHUNK;

  // persistent A fragments: afr[ks] = xnh[row0+l31][ks*16 + lh*8 .. +8]
  short8 afr[8];
  {
    int ar = min(row0 + l31, N_NODES - 1);
    const short8* ap = (const short8*)(xnh + (size_t)ar * D);
#pragma unroll
    for (int ks = 0; ks < 8; ks++) afr[ks] = ap[ks * 2 + lh];
  }

  unsigned run[16];
#pragma unroll
  for (int s = 0; s < 16; s++) run[s] = 0u;
  unsigned* kbw = kb[w];
  int srow = lane >> 1, soff = (lane & 1) * 16;

  for (int ti = 0; ti < 5; ti++) {
    int tb = cbase + ti * 128;
    __syncthreads();   // prev tile's B reads done
    {  // stage B (cols tb..tb+127) k-major; fully coalesced global reads
      int ci = tid >> 1, h = tid & 1;
      int gcol = min(tb + ci, N_NODES - 1);
      const short8* gp = (const short8*)(xnh + (size_t)gcol * D);
      short8* bp = (short8*)Bb;
#pragma unroll
      for (int i = 0; i < 8; i++) bp[(h * 8 + i) * 128 + ci] = gp[h * 8 + i];
    }
    __syncthreads();

    f32x16 acc[4];
#pragma unroll
    for (int ni = 0; ni < 4; ni++)
#pragma unroll
      for (int r = 0; r < 16; r++) acc[ni][r] = 0.f;
    const short8* bv = (const short8*)Bb;
#pragma unroll
    for (int ks = 0; ks < 8; ks++) {
      int kp = ks * 2 + lh;
#pragma unroll
      for (int ni = 0; ni < 4; ni++) {
        short8 bf = bv[kp * 128 + ni * 32 + l31];
        acc[ni] = __builtin_amdgcn_mfma_f32_32x32x16_bf16(afr[ks], bf, acc[ni], 0, 0, 0);
      }
    }

    // 4 col-subs of 32: write packed keys -> wave-local scan (no barriers)
#pragma unroll
    for (int ni = 0; ni < 4; ni++) {
      int cb2 = ti * 128 + ni * 32;
#pragma unroll
      for (int reg = 0; reg < 16; reg++) {
        int r = (reg & 3) + 8 * (reg >> 2) + 4 * lh;   // C/D row within 32
        int cic = cb2 + l31;
        unsigned bb = __float_as_uint(acc[ni][reg]);
        unsigned mu = (bb & 0x80000000u) ? ~bb : (bb | 0x80000000u);
        unsigned key = (cic < CHUNK) ? ((mu & 0xFFFFFC00u) | (unsigned)(1023 - cic)) : 0u;
        kbw[r * 35 + l31] = key;
      }
      unsigned bt[16];
      const unsigned* rp = &kbw[srow * 35 + soff];
#pragma unroll
      for (int q = 0; q < 4; q++) {
        uint4 t4 = *(const uint4*)(rp + q * 4);
        bt[q * 4 + 0] = t4.x; bt[q * 4 + 1] = t4.y;
        bt[q * 4 + 2] = t4.z; bt[q * 4 + 3] = t4.w;
      }
      sort16_asc(bt);
      merge16_asc(run, bt);
    }
  }
  // lane-pair merge (rows are 2 lanes wide): exchange sorted runs via shuffle
  {
    unsigned other[16];
#pragma unroll
    for (int s = 0; s < 16; s++) other[s] = (unsigned)__shfl_xor((int)run[s], 1);
    merge16_asc(run, other);
  }
  int grow = row0 + srow;
  if ((lane & 1) == 0 && grow < N_NODES) {
    unsigned* o = cand + ((size_t)grow * NCH + chunk) * 16;
#pragma unroll
    for (int i = 0; i < 16; i += 4)
      *(uint4*)(o + i) = make_uint4(run[i], run[i + 1], run[i + 2], run[i + 3]);
  }
}

// ---------------- merge chunk keys -> top-32 candidate cols ----------------
__global__ __launch_bounds__(64) void kmerge(const unsigned* __restrict__ cand,
                                             int* __restrict__ candIdx) {
  int row = blockIdx.x * 64 + threadIdx.x;
  if (row >= N_NODES) return;
  unsigned long long run[TOPM];
#pragma unroll
  for (int s = 0; s < TOPM; s++) run[s] = 0ull;
  const uint4* c4 = (const uint4*)(cand + (size_t)row * (NCH * 16));
  for (int ch = 0; ch < NCH; ch++) {
    unsigned b[16];
#pragma unroll
    for (int q = 0; q < 4; q++) {
      uint4 t = c4[ch * 4 + q];
      b[q * 4 + 0] = t.x; b[q * 4 + 1] = t.y;
      b[q * 4 + 2] = t.z; b[q * 4 + 3] = t.w;
    }
    unsigned base = (unsigned)(ch * CHUNK);
    unsigned long long b64[16];
#pragma unroll
    for (int s = 0; s < 16; s++) {
      unsigned k = b[s];
      unsigned gcol = base + (1023u - (k & 1023u));
      b64[s] = ((unsigned long long)(k >> 10) << 32) | (unsigned long long)(~gcol);
    }
#pragma unroll
    for (int i = 0; i < 16; i++) run[i] = max(run[i], b64[15 - i]);
#pragma unroll
    for (int j = 16; j > 0; j >>= 1)
#pragma unroll
      for (int i = 0; i < TOPM; i++)
        if ((i & j) == 0) ceu64(run[i], run[i + j]);
  }
  int4* o4 = (int4*)(candIdx + (size_t)row * TOPM);
#pragma unroll
  for (int s = 0; s < TOPM; s += 4) {
    int4 o;
    o.x = (int)(~(unsigned)(run[s + 0] & 0xFFFFFFFFull));
    o.y = (int)(~(unsigned)(run[s + 1] & 0xFFFFFFFFull));
    o.z = (int)(~(unsigned)(run[s + 2] & 0xFFFFFFFFull));
    o.w = (int)(~(unsigned)(run[s + 3] & 0xFFFFFFFFull));
    o4[s >> 2] = o;
  }
}

// ---------------- f64 exact re-rank of 32 candidates -> knn top-16 ----------------
__global__ __launch_bounds__(256) void krerank(const float* __restrict__ feats,
                                               const double* __restrict__ normD,
                                               const int* __restrict__ candIdx,
                                               int* __restrict__ knn) {
  __shared__ float rowF[D];
  __shared__ double simL[TOPM];
  __shared__ int idxL[TOPM];
  int row = blockIdx.x;
  int tid = threadIdx.x;
  if (tid < DQ)
    ((float4*)rowF)[tid] = ((const float4*)(feats + (size_t)row * D))[tid];
  int c = tid >> 3, part = tid & 7;
  int cnd = candIdx[(size_t)row * TOPM + c];
  __syncthreads();
  const float4* f4 = (const float4*)(feats + (size_t)cnd * D);
  double acc = 0.0;
#pragma unroll
  for (int g = 0; g < 4; g++) {
    float4 v = f4[part * 4 + g];
    const float* rf = &rowF[(part * 4 + g) * 4];
    acc = fma((double)v.x, (double)rf[0], acc);
    acc = fma((double)v.y, (double)rf[1], acc);
    acc = fma((double)v.z, (double)rf[2], acc);
    acc = fma((double)v.w, (double)rf[3], acc);
  }
  acc += __shfl_down(acc, 4);
  acc += __shfl_down(acc, 2);
  acc += __shfl_down(acc, 1);
  if (part == 0) {
    simL[c] = acc / (normD[row] * normD[cnd]);
    idxL[c] = cnd;
  }
  __syncthreads();
  if (tid < TOPM) {
    double s = simL[tid];
    int idx = idxL[tid];
    int rank = 0;
#pragma unroll
    for (int o = 0; o < TOPM; o++) {
      double so = simL[o];
      int io = idxL[o];
      rank += (so > s || (so == s && io < idx)) ? 1 : 0;
    }
    if (rank < TOPK) knn[(size_t)row * TOPK + rank] = idx;
  }
}

// ---------------- mult GEMM (batched, K=16, 4 branches via blockIdx.z) ----------------
// A/W staging uses (node,kg)=(q>>3,q&7): 8 consecutive lanes read 128
// contiguous bytes of one gathered row -> full 64B-line utilization (the old
// lane-per-row mapping fetched 4KB of lines per 1KB used).
__global__ __launch_bounds__(128) void kmult16x4(const float* __restrict__ feats,
    const int* __restrict__ cluster_idx, const int* __restrict__ knn,
    const float* __restrict__ wKK_c, const float* __restrict__ bKK_c,
    const float* __restrict__ wKK_n, const float* __restrict__ bKK_n,
    float* __restrict__ mult) {
  const int K = 16, NT = 128;
  __shared__ float ATl[32][132];
  __shared__ float WTl[32][K + 4];
  __shared__ int idxL[128];
  int z = blockIdx.z;
  const int* idxTab; int idxStride, idxOff;
  const float* wKK; const float* bKK;
  if (z < 3) { idxTab = cluster_idx; idxStride = NCB * 16; idxOff = z * 16; wKK = wKK_c; bKK = bKK_c; }
  else       { idxTab = knn;         idxStride = 16;       idxOff = 0;      wKK = wKK_n; bKK = bKK_n; }
  float* multBuf = mult + (size_t)z * 2560000;
  int tid = threadIdx.x;
  int i = blockIdx.y;
  int n0 = blockIdx.x * 128;
  if (tid < 128) {
    int node = n0 + tid;
    idxL[tid] = (node < N_NODES) ? idxTab[(size_t)node * idxStride + idxOff + i] : 0;
  }
  int nq = tid & 31, jq = tid >> 5;
  float acc[4][4];
#pragma unroll
  for (int m = 0; m < 4; m++)
#pragma unroll
    for (int j = 0; j < 4; j++) acc[m][j] = 0.f;
  const float4* f4 = (const float4*)feats;
  const float4* w4 = (const float4*)wKK;
  __syncthreads();
  for (int kc = 0; kc < D; kc += 32) {
    for (int q = tid; q < 1024; q += NT) {
      int node = q >> 3, kg = q & 7;      // full-line gather
      float4 val = f4[(size_t)idxL[node] * DQ + (kc >> 2) + kg];
      int kl = kg << 2;
      ATl[kl + 0][node] = val.x; ATl[kl + 1][node] = val.y;
      ATl[kl + 2][node] = val.z; ATl[kl + 3][node] = val.w;
    }
    for (int q = tid; q < K * 8; q += NT) {
      int j = q >> 3, kg = q & 7;         // full-line reads
      float4 val = w4[((size_t)i * K + j) * DQ + (kc >> 2) + kg];
      int kl = kg << 2;
      WTl[kl + 0][j] = val.x; WTl[kl + 1][j] = val.y;
      WTl[kl + 2][j] = val.z; WTl[kl + 3][j] = val.w;
    }
    __syncthreads();
#pragma unroll
    for (int k = 0; k < 32; k++) {
      float4 a = *(const float4*)&ATl[k][nq << 2];
      float4 wv = *(const float4*)&WTl[k][jq << 2];
      float am[4] = {a.x, a.y, a.z, a.w};
      float wm[4] = {wv.x, wv.y, wv.z, wv.w};
#pragma unroll
      for (int m = 0; m < 4; m++)
#pragma unroll
        for (int j = 0; j < 4; j++) acc[m][j] = fmaf(am[m], wm[j], acc[m][j]);
    }
    __syncthreads();
  }
#pragma unroll
  for (int m = 0; m < 4; m++) {
    int node = n0 + (nq << 2) + m;
    if (node < N_NODES) {
      float4 o;
      o.x = acc[m][0] + bKK[i * K + (jq << 2) + 0];
      o.y = acc[m][1] + bKK[i * K + (jq << 2) + 1];
      o.z = acc[m][2] + bKK[i * K + (jq << 2) + 2];
      o.w = acc[m][3] + bKK[i * K + (jq << 2) + 3];
      ((float4*)multBuf)[((size_t)node * K + i) * (K / 4) + jq] = o;
    }
  }
}

// ---------------- mult GEMM (K=32, struct) ----------------
template <int K>
__global__ __launch_bounds__(256) void kmult(const float* __restrict__ feats,
    const int* __restrict__ idxTab, int idxStride, int idxOff,
    const float* __restrict__ wKK, const float* __restrict__ bKK,
    float* __restrict__ multBuf) {
  constexpr int NT = 8 * K;
  constexpr int JG = K / 4;
  __shared__ float ATl[32][132];
  __shared__ float WTl[32][K + 4];
  __shared__ int idxL[128];
  int tid = threadIdx.x;
  int i = blockIdx.y;
  int n0 = blockIdx.x * 128;
  if (tid < 128) {
    int node = n0 + tid;
    idxL[tid] = (node < N_NODES) ? idxTab[(size_t)node * idxStride + idxOff + i] : 0;
  }
  int nq = tid & 31, jq = tid >> 5;
  float acc[4][4];
#pragma unroll
  for (int m = 0; m < 4; m++)
#pragma unroll
    for (int j = 0; j < 4; j++) acc[m][j] = 0.f;
  const float4* f4 = (const float4*)feats;
  const float4* w4 = (const float4*)wKK;
  __syncthreads();
  for (int kc = 0; kc < D; kc += 32) {
    for (int q = tid; q < 1024; q += NT) {
      int node = q >> 3, kg = q & 7;      // full-line gather
      float4 val = f4[(size_t)idxL[node] * DQ + (kc >> 2) + kg];
      int kl = kg << 2;
      ATl[kl + 0][node] = val.x; ATl[kl + 1][node] = val.y;
      ATl[kl + 2][node] = val.z; ATl[kl + 3][node] = val.w;
    }
    for (int q = tid; q < K * 8; q += NT) {
      int j = q >> 3, kg = q & 7;         // full-line reads
      float4 val = w4[((size_t)i * K + j) * DQ + (kc >> 2) + kg];
      int kl = kg << 2;
      WTl[kl + 0][j] = val.x; WTl[kl + 1][j] = val.y;
      WTl[kl + 2][j] = val.z; WTl[kl + 3][j] = val.w;
    }
    __syncthreads();
#pragma unroll
    for (int k = 0; k < 32; k++) {
      float4 a = *(const float4*)&ATl[k][nq << 2];
      float4 wv = *(const float4*)&WTl[k][jq << 2];
      float am[4] = {a.x, a.y, a.z, a.w};
      float wm[4] = {wv.x, wv.y, wv.z, wv.w};
#pragma unroll
      for (int m = 0; m < 4; m++)
#pragma unroll
        for (int j = 0; j < 4; j++) acc[m][j] = fmaf(am[m], wm[j], acc[m][j]);
    }
    __syncthreads();
  }
#pragma unroll
  for (int m = 0; m < 4; m++) {
    int node = n0 + (nq << 2) + m;
    if (node < N_NODES) {
      float4 o;
      o.x = acc[m][0] + bKK[i * K + (jq << 2) + 0];
      o.y = acc[m][1] + bKK[i * K + (jq << 2) + 1];
      o.z = acc[m][2] + bKK[i * K + (jq << 2) + 2];
      o.w = acc[m][3] + bKK[i * K + (jq << 2) + 3];
      ((float4*)multBuf)[((size_t)node * K + i) * JG + jq] = o;
    }
  }
}

// ---------------- softmax + coef + gather-combine (batched K=16) ----------------
__global__ __launch_bounds__(256) void kvconv16x4(const float* __restrict__ feats,
    const int* __restrict__ cluster_idx, const int* __restrict__ knn,
    const float* __restrict__ mult,
    const float* __restrict__ wK1_c, const float* __restrict__ bK1_c,
    const float* __restrict__ wK1_n, const float* __restrict__ bK1_n,
    float* __restrict__ hx) {
  const int K = 16;
  __shared__ float multL[8][K][K + 1];
  __shared__ float aL[8][K];
  __shared__ float coefL[8][K];
  __shared__ int idxL[8][K];
  int z = blockIdx.y;
  const int* idxTab; int idxStride, idxOff;
  const float* wK1; const float* bK1p;
  if (z < 3) { idxTab = cluster_idx; idxStride = NCB * 16; idxOff = z * 16; wK1 = wK1_c; bK1p = bK1_c; }
  else       { idxTab = knn;         idxStride = 16;       idxOff = 0;      wK1 = wK1_n; bK1p = bK1_n; }
  const float* multBuf = mult + (size_t)z * 2560000;
  int tslot = z;
  int tid = threadIdx.x;
  int n0 = blockIdx.x * 8;
  for (int q = tid; q < 8 * K; q += 256) {
    int nn = q / K, j = q & (K - 1);
    int node = n0 + nn;
    idxL[nn][j] = (node < N_NODES) ? idxTab[(size_t)node * idxStride + idxOff + j] : 0;
  }
  for (int q = tid; q < 8 * K * K; q += 256) {
    int nn = q / (K * K);
    int rem = q - nn * K * K;
    int node = n0 + nn;
    multL[nn][rem / K][rem & (K - 1)] = (node < N_NODES) ? multBuf[(size_t)node * K * K + rem] : 0.f;
  }
  __syncthreads();
  for (int q = tid; q < 8 * K; q += 256) {
    int nn = q / K, ii = q & (K - 1);
    float mx = -1e30f;
    for (int j = 0; j < K; j++) mx = fmaxf(mx, multL[nn][ii][j]);
    float s = 0.f;
    for (int j = 0; j < K; j++) {
      float e = expf(multL[nn][ii][j] - mx);
      multL[nn][ii][j] = e;
      s += e;
    }
    aL[nn][ii] = wK1[ii] / s;
  }
  __syncthreads();
  for (int q = tid; q < 8 * K; q += 256) {
    int nn = q / K, j = q & (K - 1);
    float cs = 0.f;
    for (int ii = 0; ii < K; ii++) cs = fmaf(aL[nn][ii], multL[nn][ii][j], cs);
    coefL[nn][j] = cs;
  }
  __syncthreads();
  {
    int nn = tid >> 5, dq = tid & 31;
    int node = n0 + nn;
    if (node < N_NODES) {
      float bk1 = bK1p[0];
      float4 accv = make_float4(bk1, bk1, bk1, bk1);
      const float4* f4 = (const float4*)feats;
      for (int j = 0; j < K; j++) {
        float cf = coefL[nn][j];
        float4 xv = f4[(size_t)idxL[nn][j] * DQ + dq];
        accv.x = fmaf(cf, xv.x, accv.x);
        accv.y = fmaf(cf, xv.y, accv.y);
        accv.z = fmaf(cf, xv.z, accv.z);
        accv.w = fmaf(cf, xv.w, accv.w);
      }
      ((float4*)hx)[((size_t)node * T_HE + tslot) * DQ + dq] = accv;
    }
  }
}

// ---------------- softmax + coef + gather-combine (K=32, struct) ----------------
template <int K>
__global__ __launch_bounds__(256) void kvconv2(const float* __restrict__ feats,
    const int* __restrict__ idxTab, int idxStride, int idxOff,
    const float* __restrict__ multBuf, const float* __restrict__ wK1,
    const float* __restrict__ bK1p, float* __restrict__ hx, int tslot) {
  __shared__ float multL[8][K][K + 1];
  __shared__ float aL[8][K];
  __shared__ float coefL[8][K];
  __shared__ int idxL[8][K];
  int tid = threadIdx.x;
  int n0 = blockIdx.x * 8;
  for (int q = tid; q < 8 * K; q += 256) {
    int nn = q / K, j = q & (K - 1);
    int node = n0 + nn;
    idxL[nn][j] = (node < N_NODES) ? idxTab[(size_t)node * idxStride + idxOff + j] : 0;
  }
  for (int q = tid; q < 8 * K * K; q += 256) {
    int nn = q / (K * K);
    int rem = q - nn * K * K;
    int node = n0 + nn;
    multL[nn][rem / K][rem & (K - 1)] = (node < N_NODES) ? multBuf[(size_t)node * K * K + rem] : 0.f;
  }
  __syncthreads();
  for (int q = tid; q < 8 * K; q += 256) {
    int nn = q / K, ii = q & (K - 1);
    float mx = -1e30f;
    for (int j = 0; j < K; j++) mx = fmaxf(mx, multL[nn][ii][j]);
    float s = 0.f;
    for (int j = 0; j < K; j++) {
      float e = expf(multL[nn][ii][j] - mx);
      multL[nn][ii][j] = e;
      s += e;
    }
    aL[nn][ii] = wK1[ii] / s;
  }
  __syncthreads();
  for (int q = tid; q < 8 * K; q += 256) {
    int nn = q / K, j = q & (K - 1);
    float cs = 0.f;
    for (int ii = 0; ii < K; ii++) cs = fmaf(aL[nn][ii], multL[nn][ii][j], cs);
    coefL[nn][j] = cs;
  }
  __syncthreads();
  {
    int nn = tid >> 5, dq = tid & 31;
    int node = n0 + nn;
    if (node < N_NODES) {
      float bk1 = bK1p[0];
      float4 accv = make_float4(bk1, bk1, bk1, bk1);
      const float4* f4 = (const float4*)feats;
      for (int j = 0; j < K; j++) {
        float cf = coefL[nn][j];
        float4 xv = f4[(size_t)idxL[nn][j] * DQ + dq];
        accv.x = fmaf(cf, xv.x, accv.x);
        accv.y = fmaf(cf, xv.y, accv.y);
        accv.z = fmaf(cf, xv.z, accv.z);
        accv.w = fmaf(cf, xv.w, accv.w);
      }
      ((float4*)hx)[((size_t)node * T_HE + tslot) * DQ + dq] = accv;
    }
  }
}

// ---------------- edge attention + fc ----------------
__global__ __launch_bounds__(256) void kfinal(const float* __restrict__ hx,
    const float* __restrict__ w1, const float* __restrict__ b1,
    const float* __restrict__ w2, const float* __restrict__ b2p,
    const float* __restrict__ fcw, const float* __restrict__ fcb,
    float* __restrict__ out) {
  __shared__ float xL[8][T_HE][D];
  __shared__ float hL[8][T_HE][HID_SZ];
  __shared__ float scL[8][T_HE];
  __shared__ float aggL[8][D];
  int tid = threadIdx.x;
  int n0 = blockIdx.x * 8;
  const float4* hx4 = (const float4*)hx;
  for (int q = tid; q < 8 * T_HE * DQ; q += 256) {
    int nn = q / (T_HE * DQ);
    int rem = q - nn * (T_HE * DQ);
    int t = rem / DQ;
    int dq = rem & 31;
    int node = n0 + nn;
    float4 val = make_float4(0.f, 0.f, 0.f, 0.f);
    if (node < N_NODES) val = hx4[((size_t)node * T_HE + t) * DQ + dq];
    *(float4*)&xL[nn][t][dq << 2] = val;
  }
  __syncthreads();
  for (int q = tid; q < 8 * T_HE * HID_SZ; q += 256) {
    int nn = q / (T_HE * HID_SZ);
    int rem = q - nn * (T_HE * HID_SZ);
    int t = rem / HID_SZ;
    int hh = rem & (HID_SZ - 1);
    float acc = b1[hh];
    for (int d = 0; d < D; d++) acc = fmaf(xL[nn][t][d], w1[d * HID_SZ + hh], acc);
    hL[nn][t][hh] = fmaxf(acc, 0.f);
  }
  __syncthreads();
  if (tid < 8 * T_HE) {
    int nn = tid / T_HE, t = tid % T_HE;
    float acc = b2p[0];
    for (int hh = 0; hh < HID_SZ; hh++) acc = fmaf(hL[nn][t][hh], w2[hh], acc);
    scL[nn][t] = acc;
  }
  __syncthreads();
  if (tid < 8) {
    float mx = -1e30f;
#pragma unroll
    for (int t = 0; t < T_HE; t++) mx = fmaxf(mx, scL[tid][t]);
    float e[T_HE];
    float s = 0.f;
#pragma unroll
    for (int t = 0; t < T_HE; t++) { e[t] = expf(scL[tid][t] - mx); s += e[t]; }
    float inv = 1.f / s;
#pragma unroll
    for (int t = 0; t < T_HE; t++) scL[tid][t] = e[t] * inv;
  }
  __syncthreads();
  {
    int nn = tid >> 5, dq = tid & 31;
    float4 acc = make_float4(0.f, 0.f, 0.f, 0.f);
#pragma unroll
    for (int t = 0; t < T_HE; t++) {
      float sw = scL[nn][t];
      float4 xv = *(const float4*)&xL[nn][t][dq << 2];
      acc.x = fmaf(sw, xv.x, acc.x);
      acc.y = fmaf(sw, xv.y, acc.y);
      acc.z = fmaf(sw, xv.z, acc.z);
      acc.w = fmaf(sw, xv.w, acc.w);
    }
    *(float4*)&aggL[nn][dq << 2] = acc;
  }
  __syncthreads();
  {
    int dout = tid & 127, g = tid >> 7;
    float a0 = fcb[dout], a1 = a0, a2 = a0, a3 = a0;
    for (int d = 0; d < D; d++) {
      float w = fcw[d * 128 + dout];
      a0 = fmaf(aggL[g * 4 + 0][d], w, a0);
      a1 = fmaf(aggL[g * 4 + 1][d], w, a1);
      a2 = fmaf(aggL[g * 4 + 2][d], w, a2);
      a3 = fmaf(aggL[g * 4 + 3][d], w, a3);
    }
    int nb = n0 + g * 4;
    if (nb + 0 < N_NODES) out[(size_t)(nb + 0) * 128 + dout] = fmaxf(a0, 0.f);
    if (nb + 1 < N_NODES) out[(size_t)(nb + 1) * 128 + dout] = fmaxf(a1, 0.f);
    if (nb + 2 < N_NODES) out[(size_t)(nb + 2) * 128 + dout] = fmaxf(a2, 0.f);
    if (nb + 3 < N_NODES) out[(size_t)(nb + 3) * 128 + dout] = fmaxf(a3, 0.f);
  }
}

extern "C" void kernel_launch(void* const* d_in, const int* in_sizes, int n_in,
                              void* d_out, int out_size, void* d_ws, size_t ws_size,
                              hipStream_t stream) {
  (void)in_sizes; (void)n_in; (void)out_size; (void)ws_size;
  const float* feats       = (const float*)d_in[1];
  const int*   cluster_idx = (const int*)d_in[2];
  const int*   struct_idx  = (const int*)d_in[3];
  const float* wKK_c = (const float*)d_in[5];
  const float* bKK_c = (const float*)d_in[6];
  const float* wK1_c = (const float*)d_in[7];
  const float* bK1_c = (const float*)d_in[8];
  const float* wKK_n = (const float*)d_in[9];
  const float* bKK_n = (const float*)d_in[10];
  const float* wK1_n = (const float*)d_in[11];
  const float* bK1_n = (const float*)d_in[12];
  const float* wKK_s = (const float*)d_in[13];
  const float* bKK_s = (const float*)d_in[14];
  const float* wK1_s = (const float*)d_in[15];
  const float* bK1_s = (const float*)d_in[16];
  const float* ec_w1 = (const float*)d_in[17];
  const float* ec_b1 = (const float*)d_in[18];
  const float* ec_w2 = (const float*)d_in[19];
  const float* ec_b2 = (const float*)d_in[20];
  const float* fc_w  = (const float*)d_in[21];
  const float* fc_b  = (const float*)d_in[22];
  float* out = (float*)d_out;

  // ws layout (lifetime-overlapped, total 72.32 MB — proven fits):
  //  [0, 2.56M)        xnh (bf16)     dead after ksim
  //  [2.56M, 12.8M)    cand (u32)     dead after kmerge
  //  [12.8M, 14.08M)   candIdx (int)  dead after krerank
  //  [14.08M, 14.16M)  normD (f64)    dead after krerank
  //  [0, 40.96M)       mult (f32)     written after krerank (4x2.56M floats K=16; reused for K=32)
  //  [46.08M, 46.72M)  knn (int)
  //  [46.72M, 72.32M)  hx (f32)
  char* wsb = (char*)d_ws;
  unsigned short* xnh = (unsigned short*)(wsb);
  unsigned* cand = (unsigned*)(wsb + 2560000);
  int* candIdx = (int*)(wsb + 12800000);
  double* normD = (double*)(wsb + 14080000);
  float* mult = (float*)(wsb);
  int* knnIdx = (int*)(wsb + 46080000);
  float* hx = (float*)(wsb + 46720000);

  knorm<<<N_NODES, 64, 0, stream>>>(feats, xnh, normD);
  ksim<<<dim3(79, NCH), 256, 0, stream>>>(xnh, cand);
  kmerge<<<(N_NODES + 63) / 64, 64, 0, stream>>>(cand, candIdx);
  krerank<<<N_NODES, 256, 0, stream>>>(feats, normD, candIdx, knnIdx);

  kmult16x4<<<dim3(79, 16, 4), 128, 0, stream>>>(feats, cluster_idx, knnIdx,
                                                 wKK_c, bKK_c, wKK_n, bKK_n, mult);
  kvconv16x4<<<dim3(1250, 4), 256, 0, stream>>>(feats, cluster_idx, knnIdx, mult,
                                                wK1_c, bK1_c, wK1_n, bK1_n, hx);
  kmult<32><<<dim3(79, 32), 256, 0, stream>>>(feats, struct_idx, 32, 0, wKK_s, bKK_s, mult);
  kvconv2<32><<<1250, 256, 0, stream>>>(feats, struct_idx, 32, 0, mult, wK1_s, bK1_s, hx, 4);

  kfinal<<<1250, 256, 0, stream>>>(hx, ec_w1, ec_b1, ec_w2, ec_b2, fc_w, fc_b, out);
}